// Round 3
// baseline (2243.437 us; speedup 1.0000x reference)
//
#include <hip/hip_runtime.h>
#include <cstdint>
#include <cstddef>

typedef __attribute__((ext_vector_type(8))) short short8x;
typedef __attribute__((ext_vector_type(4))) float f32x4;

static constexpr int NN = 20000;
static constexpr int EE = 640000;

#define DEVI __device__ __forceinline__

DEVI float b2f(uint16_t u){ union{uint32_t i; float f;} x; x.i = (uint32_t)u<<16; return x.f; }
DEVI uint16_t f2b(float f){ union{float f; uint32_t i;} x; x.f=f; uint32_t i=x.i;
  return (uint16_t)((i + 0x7FFFu + ((i>>16)&1u))>>16); }
DEVI float silu_f(float v){ return v / (1.f + __expf(-v)); }

// ---------------- generic 128-col MFMA GEMM ----------------
// C[M,128] = epi( A[M,K] @ W[K,128] + bias*bias_scale )
// A is f32 (AF32=1) or bf16 (AF32=0); staged to LDS as bf16 either way.
// Wt pre-transposed bf16: Wt[c*K + k] = W[k*128 + c]
// EPI: 0=store bf16, 1=store f32, 2=outf += v, 3=outf = resid + rs*v (f32)
// In-place (A==out) is safe: each block stages its whole 128-row A tile to LDS
// before the epilogue writes, and blocks own disjoint row ranges.
template<int AF32, int EPI, int SILU>
__global__ __launch_bounds__(256) void gemm128(
    const void* Ap, const uint16_t* __restrict__ Wt,
    const float* __restrict__ bias, float bias_scale,
    int M, int K,
    uint16_t* outb, float* outf,
    const float* __restrict__ resid, float resid_scale)
{
  __shared__ uint16_t Als[128*136];
  __shared__ uint16_t Wls[128*136];
  const int t = threadIdx.x;
  const int row0 = blockIdx.x * 128;
  const int w = t >> 6, l = t & 63;
  const int lr = l & 15, lk = (l>>4)*8;

  f32x4 acc[2][8];
#pragma unroll
  for (int a=0;a<2;a++)
#pragma unroll
    for(int b=0;b<8;b++) acc[a][b] = (f32x4){0.f,0.f,0.f,0.f};

  for (int kc = 0; kc < K; kc += 128){
#pragma unroll
    for (int i=0;i<8;i++){                  // stage A tile 128x128 -> bf16 LDS
      int c = t + i*256;
      int r = c >> 4, k8 = (c & 15)*8;
      int gr = row0 + r;
      if (AF32){
        float4 a = {0.f,0.f,0.f,0.f}, b = {0.f,0.f,0.f,0.f};
        if (gr < M){
          const float* Af = (const float*)Ap + (size_t)gr*K + kc + k8;
          a = *(const float4*)Af;
          b = *(const float4*)(Af + 4);
        }
        union { uint16_t u[8]; uint4 v; } pk;
        pk.u[0]=f2b(a.x); pk.u[1]=f2b(a.y); pk.u[2]=f2b(a.z); pk.u[3]=f2b(a.w);
        pk.u[4]=f2b(b.x); pk.u[5]=f2b(b.y); pk.u[6]=f2b(b.z); pk.u[7]=f2b(b.w);
        *(uint4*)(&Als[r*136 + k8]) = pk.v;
      } else {
        uint4 v = {0u,0u,0u,0u};
        if (gr < M) v = *(const uint4*)((const uint16_t*)Ap + (size_t)gr*K + kc + k8);
        *(uint4*)(&Als[r*136 + k8]) = v;
      }
    }
#pragma unroll
    for (int i=0;i<8;i++){                  // stage Wt tile 128x128 (bf16)
      int c = t + i*256;
      int r = c >> 4, k8 = (c & 15)*8;
      uint4 v = *(const uint4*)(Wt + (size_t)r*K + kc + k8);
      *(uint4*)(&Wls[r*136 + k8]) = v;
    }
    __syncthreads();
#pragma unroll
    for (int kt=0; kt<4; ++kt){
      int kb = kt*32 + lk;
      short8x bfr[8];
#pragma unroll
      for (int c16=0;c16<8;c16++) bfr[c16] = *(const short8x*)(&Wls[(c16*16+lr)*136 + kb]);
#pragma unroll
      for (int r16=0;r16<2;r16++){
        short8x afr = *(const short8x*)(&Als[(w*32 + r16*16 + lr)*136 + kb]);
#pragma unroll
        for (int c16=0;c16<8;c16++)
          acc[r16][c16] = __builtin_amdgcn_mfma_f32_16x16x32_bf16(afr, bfr[c16], acc[r16][c16], 0,0,0);
      }
    }
    __syncthreads();
  }

  float bb[8];
#pragma unroll
  for (int c16=0;c16<8;c16++) bb[c16] = bias[c16*16+lr] * bias_scale;
#pragma unroll
  for (int r16=0;r16<2;r16++){
#pragma unroll
    for (int j=0;j<4;j++){
      int row = row0 + w*32 + r16*16 + (l>>4)*4 + j;
      if (row >= M) continue;
#pragma unroll
      for (int c16=0;c16<8;c16++){
        int col = c16*16 + lr;
        float v = acc[r16][c16][j] + bb[c16];
        if (SILU) v = silu_f(v);
        size_t o = (size_t)row*128 + col;
        if (EPI==0)      outb[o] = f2b(v);
        else if (EPI==1) outf[o] = v;
        else if (EPI==2) outf[o] += v;
        else             outf[o] = resid[o] + resid_scale*v;
      }
    }
  }
}

// ---------------- row LayerNorm (128 cols) ----------------
template<typename Tin, typename Tout>
__global__ __launch_bounds__(256) void ln_kernel(const Tin* in, Tout* out, int M)
{
  int wv = threadIdx.x >> 6, l = threadIdx.x & 63;
  int row = blockIdx.x*4 + wv;
  if (row >= M) return;
  float a, b;
  if constexpr (sizeof(Tin)==4){
    float2 v = *(const float2*)((const float*)in + (size_t)row*128 + 2*l);
    a = v.x; b = v.y;
  } else {
    uint32_t v = *(const uint32_t*)((const uint16_t*)in + (size_t)row*128 + 2*l);
    a = b2f((uint16_t)(v & 0xFFFFu)); b = b2f((uint16_t)(v >> 16));
  }
  float s = a + b, q = a*a + b*b;
#pragma unroll
  for (int d=1; d<64; d<<=1){ s += __shfl_xor(s, d); q += __shfl_xor(q, d); }
  float m = s * 0.0078125f;
  float var = fmaxf(q * 0.0078125f - m*m, 0.f);
  float rstd = rsqrtf(var + 1e-5f);
  float ra = (a-m)*rstd, rb = (b-m)*rstd;
  if constexpr (sizeof(Tout)==4){
    *(float2*)((float*)out + (size_t)row*128 + 2*l) = make_float2(ra, rb);
  } else {
    uint32_t pack = (uint32_t)f2b(ra) | ((uint32_t)f2b(rb) << 16);
    *(uint32_t*)((uint16_t*)out + (size_t)row*128 + 2*l) = pack;
  }
}

// ---------------- per-node gather aggregation ----------------
// node i = blockIdx.x, feature f = threadIdx.x (128 threads)
// msg = z[i]*x1[other]*ea[e] (sign-flipped on f>=64 if INV); ea is f32
// stats(bf16): [mean | std | max | min] at stats[i*512 + {0,128,256,384} + f]
// EUPD: ea[e] *= (1 + h3[o]*h4[i] + h3[i]*h4[o]) in place (f32)
template<int INV, int EUPD, int ACCUM>
__global__ __launch_bounds__(128) void agg_kernel(
    const float* ea, float* ea_out,
    const uint16_t* __restrict__ x1, const uint16_t* __restrict__ z,
    const uint16_t* __restrict__ h3, const uint16_t* __restrict__ h4,
    const int* __restrict__ eids, const int* __restrict__ ptr,
    const int* __restrict__ other, uint16_t* stats)
{
  __shared__ int se[128];
  __shared__ int so[128];
  int i = blockIdx.x, f = threadIdx.x;
  size_t ib = (size_t)i*128 + f;
  float zi = b2f(z[ib]);
  float h3i = 0.f, h4i = 0.f;
  if (EUPD){ h3i = b2f(h3[ib]); h4i = b2f(h4[ib]); }
  int beg = ptr[i], end = ptr[i+1];
  float s=0.f, s2=0.f, mx=-3.4e38f, mn=3.4e38f;
  for (int jb = beg; jb < end; jb += 128){
    int cn = min(128, end - jb);
    if (f < cn){ int e = eids[jb+f]; se[f] = e; so[f] = other[e]; }
    __syncthreads();
#pragma unroll 4
    for (int jj = 0; jj < cn; ++jj){
      int e = se[jj], o = so[jj];
      float x1v = b2f(x1[(size_t)o*128 + f]);
      float eav = ea[(size_t)e*128 + f];
      float m = zi * x1v * eav;
      if (INV){ if (f >= 64) m = -m; }
      s += m; s2 += m*m; mx = fmaxf(mx, m); mn = fminf(mn, m);
      if (EUPD){
        float h3o = b2f(h3[(size_t)o*128 + f]);
        float h4o = b2f(h4[(size_t)o*128 + f]);
        ea_out[(size_t)e*128 + f] = eav * (1.f + h3o*h4i + h3i*h4o);
      }
    }
    __syncthreads();
  }
  int cnt = end - beg;
  float dn = cnt > 0 ? 1.f/(float)cnt : 1.f;
  float mean = s*dn, m2 = s2*dn;
  float sd = sqrtf(fmaxf(m2 - mean*mean, 0.f) + 1e-5f);
  if (cnt == 0){ mx = 0.f; mn = 0.f; }
  size_t o0 = (size_t)i*512 + f;
  if (ACCUM){
    stats[o0    ] = f2b(b2f(stats[o0    ]) + mean);
    stats[o0+128] = f2b(b2f(stats[o0+128]) + sd);
    stats[o0+256] = f2b(b2f(stats[o0+256]) + mx);
    stats[o0+384] = f2b(b2f(stats[o0+384]) + mn);
  } else {
    stats[o0]=f2b(mean); stats[o0+128]=f2b(sd); stats[o0+256]=f2b(mx); stats[o0+384]=f2b(mn);
  }
}

// ---------------- CSR build ----------------
__global__ void count_deg(const int* __restrict__ ei, int* cnt_src, int* cnt_dst){
  int e = blockIdx.x*256 + threadIdx.x;
  if (e < EE){
    atomicAdd(&cnt_src[ei[e]], 1);
    atomicAdd(&cnt_dst[ei[EE+e]], 1);
  }
}

__global__ __launch_bounds__(1024) void scan_excl(const int* __restrict__ cnt, int* ptr, int n){
  __shared__ int buf[1024];
  __shared__ int carry;
  int t = threadIdx.x;
  if (t==0) carry = 0;
  __syncthreads();
  for (int base=0; base<n; base+=1024){
    int v = (base+t < n) ? cnt[base+t] : 0;
    int acc = v;
    buf[t] = acc;
    __syncthreads();
    for (int s=1; s<1024; s<<=1){
      int add = (t>=s) ? buf[t-s] : 0;
      __syncthreads();
      acc += add;
      buf[t] = acc;
      __syncthreads();
    }
    if (base+t < n) ptr[base+t] = carry + acc - v;
    int tot = buf[1023];
    __syncthreads();
    if (t==0) carry += tot;
    __syncthreads();
  }
  if (t==0) ptr[n] = carry;
}

__global__ void init_cursor(const int* p1, int* c1, const int* p2, int* c2, int n){
  int i = blockIdx.x*256 + threadIdx.x;
  if (i < n){ c1[i] = p1[i]; c2[i] = p2[i]; }
}

__global__ void scatter_edges(const int* __restrict__ ei, int* cur_src, int* cur_dst,
                              int* eid_src, int* eid_dst){
  int e = blockIdx.x*256 + threadIdx.x;
  if (e < EE){
    int s = ei[e], d = ei[EE+e];
    eid_src[atomicAdd(&cur_src[s],1)] = e;
    eid_dst[atomicAdd(&cur_dst[d],1)] = e;
  }
}

// ------- weight transpose+cast: W[m][k][c] (f32) -> Wt[m][c][k] (bf16) -------
__global__ void transpose_w(const float* __restrict__ W, uint16_t* __restrict__ Wt,
                            int K, int total){
  int idx = blockIdx.x*256 + threadIdx.x;
  if (idx < total){
    int per = K*128;
    int m = idx / per, r = idx - m*per;
    int k = r >> 7, c = r & 127;
    Wt[(size_t)m*per + (size_t)c*K + k] = f2b(W[idx]);
  }
}

extern "C" void kernel_launch(void* const* d_in, const int* in_sizes, int n_in,
                              void* d_out, int out_size, void* d_ws, size_t ws_size,
                              hipStream_t stream)
{
  const float* x    = (const float*)d_in[0];
  const float* eatt = (const float*)d_in[1];
  const float* Wn   = (const float*)d_in[2];
  const float* bn   = (const float*)d_in[3];
  const float* We   = (const float*)d_in[4];
  const float* be   = (const float*)d_in[5];
  const float* W1   = (const float*)d_in[6];
  const float* b1   = (const float*)d_in[7];
  const float* W2   = (const float*)d_in[8];
  const float* b2   = (const float*)d_in[9];
  const float* W3   = (const float*)d_in[10];
  const float* b3   = (const float*)d_in[11];
  const float* W4   = (const float*)d_in[12];
  const float* b4   = (const float*)d_in[13];
  const float* Wd   = (const float*)d_in[14];
  const float* bd   = (const float*)d_in[15];
  const float* Wnd1 = (const float*)d_in[16];
  const float* bnd1 = (const float*)d_in[17];
  const float* Wnd2 = (const float*)d_in[18];
  const float* bnd2 = (const float*)d_in[19];
  const float* Wed1 = (const float*)d_in[20];
  const float* bed1 = (const float*)d_in[21];
  const float* Wed2 = (const float*)d_in[22];
  const float* bed2 = (const float*)d_in[23];
  const int* ei     = (const int*)d_in[24];

  float* out_node = (float*)d_out;
  float* out_edge = out_node + (size_t)NN*128;

  // ea lives (as f32) in the out_edge region: EE*128 floats, exactly its size.
  // Fully overwritten by the encoder each call; final in-place GEMM chain is
  // row-tiled and same-element-size -> race-free.
  float* ea = out_edge;

  char* p = (char*)d_ws;
  auto alloc = [&](size_t bytes)->char*{
    char* r = p; p += (bytes + 255) & ~(size_t)255; return r; };

  float*    hidden = (float*)   alloc((size_t)NN*128*4);
  uint16_t* hn     = (uint16_t*)alloc((size_t)NN*128*2);
  uint16_t* x1b    = (uint16_t*)alloc((size_t)NN*128*2);
  uint16_t* zb     = (uint16_t*)alloc((size_t)NN*128*2);
  uint16_t* h3b    = (uint16_t*)alloc((size_t)NN*128*2);
  uint16_t* h4b    = (uint16_t*)alloc((size_t)NN*128*2);
  uint16_t* stats  = (uint16_t*)alloc((size_t)NN*512*2);
  int* cnt_src = (int*)alloc((size_t)NN*4);
  int* cnt_dst = (int*)alloc((size_t)NN*4);
  int* ptr_src = (int*)alloc((size_t)(NN+1)*4);
  int* ptr_dst = (int*)alloc((size_t)(NN+1)*4);
  int* cur_src = (int*)alloc((size_t)NN*4);
  int* cur_dst = (int*)alloc((size_t)NN*4);
  int* eid_src = (int*)alloc((size_t)EE*4);
  int* eid_dst = (int*)alloc((size_t)EE*4);
  uint16_t* WT = (uint16_t*)alloc((size_t)491520*2);

  uint16_t* wnT   = WT;
  uint16_t* weT   = WT + 16384;
  uint16_t* w1T   = WT + 32768;
  uint16_t* w2T   = WT + 81920;
  uint16_t* w3T   = WT + 131072;
  uint16_t* w4T   = WT + 180224;
  uint16_t* wdT   = WT + 229376;
  uint16_t* wnd1T = WT + 425984;
  uint16_t* wnd2T = WT + 442368;
  uint16_t* wed1T = WT + 458752;
  uint16_t* wed2T = WT + 475136;

  // ---- CSR build ----
  hipMemsetAsync(cnt_src, 0, (size_t)NN*4, stream);
  hipMemsetAsync(cnt_dst, 0, (size_t)NN*4, stream);
  count_deg<<<(EE+255)/256, 256, 0, stream>>>(ei, cnt_src, cnt_dst);
  scan_excl<<<1, 1024, 0, stream>>>(cnt_src, ptr_src, NN);
  scan_excl<<<1, 1024, 0, stream>>>(cnt_dst, ptr_dst, NN);
  init_cursor<<<(NN+255)/256, 256, 0, stream>>>(ptr_src, cur_src, ptr_dst, cur_dst, NN);
  scatter_edges<<<(EE+255)/256, 256, 0, stream>>>(ei, cur_src, cur_dst, eid_src, eid_dst);

  // ---- transpose+cast weights ----
  transpose_w<<<64, 256, 0, stream>>>(Wn, wnT, 128, 16384);
  transpose_w<<<64, 256, 0, stream>>>(We, weT, 128, 16384);
  transpose_w<<<192, 256, 0, stream>>>(W1, w1T, 128, 49152);
  transpose_w<<<192, 256, 0, stream>>>(W2, w2T, 128, 49152);
  transpose_w<<<192, 256, 0, stream>>>(W3, w3T, 128, 49152);
  transpose_w<<<192, 256, 0, stream>>>(W4, w4T, 128, 49152);
  transpose_w<<<768, 256, 0, stream>>>(Wd, wdT, 512, 196608);
  transpose_w<<<64, 256, 0, stream>>>(Wnd1, wnd1T, 128, 16384);
  transpose_w<<<64, 256, 0, stream>>>(Wnd2, wnd2T, 128, 16384);
  transpose_w<<<64, 256, 0, stream>>>(Wed1, wed1T, 128, 16384);
  transpose_w<<<64, 256, 0, stream>>>(Wed2, wed2T, 128, 16384);

  const int gN = (NN+127)/128, gE = EE/128;

  // ---- encoders (A = f32 inputs) ----
  gemm128<1,1,0><<<gN, 256, 0, stream>>>(x, wnT, bn, 1.f, NN, 128, nullptr, hidden, nullptr, 0.f);
  gemm128<1,1,0><<<gE, 256, 0, stream>>>(eatt, weT, be, 1.f, EE, 128, nullptr, ea, nullptr, 0.f);

  // ---- layers ----
  for (int lyr = 0; lyr < 3; ++lyr){
    const uint16_t* w1l = w1T + lyr*16384;
    const uint16_t* w2l = w2T + lyr*16384;
    const uint16_t* w3l = w3T + lyr*16384;
    const uint16_t* w4l = w4T + lyr*16384;
    const uint16_t* wdl = wdT + lyr*65536;
    const float* b1l = b1 + lyr*128;
    const float* b2l = b2 + lyr*128;
    const float* b3l = b3 + lyr*128;
    const float* b4l = b4 + lyr*128;
    const float* bdl = bd + lyr*128;

    ln_kernel<float,uint16_t><<<(NN+3)/4, 256, 0, stream>>>(hidden, hn, NN);
    gemm128<0,0,1><<<gN, 256, 0, stream>>>(hn, w1l, b1l, 1.f, NN, 128, x1b, nullptr, nullptr, 0.f);
    gemm128<0,0,1><<<gN, 256, 0, stream>>>(hn, w2l, b2l, 1.f, NN, 128, zb,  nullptr, nullptr, 0.f);
    gemm128<0,0,1><<<gN, 256, 0, stream>>>(hn, w3l, b3l, 1.f, NN, 128, h3b, nullptr, nullptr, 0.f);
    gemm128<0,0,1><<<gN, 256, 0, stream>>>(hn, w4l, b4l, 1.f, NN, 128, h4b, nullptr, nullptr, 0.f);

    // src-direction aggregation (with inv sign), writes stats
    agg_kernel<1,0,0><<<NN, 128, 0, stream>>>(ea, nullptr, x1b, zb, nullptr, nullptr,
                                              eid_src, ptr_src, ei + EE, stats);
    // dst-direction aggregation, accumulates stats, fused in-place ea update
    agg_kernel<0,1,1><<<NN, 128, 0, stream>>>(ea, ea, x1b, zb, h3b, h4b,
                                              eid_dst, ptr_dst, ei, stats);
    // hidden += stats @ Wd + 2*bd
    gemm128<0,2,0><<<gN, 256, 0, stream>>>(stats, wdl, bdl, 2.f, NN, 512, nullptr, hidden, nullptr, 0.f);
  }

  // ---- node decoder ----
  ln_kernel<float,uint16_t><<<(NN+3)/4, 256, 0, stream>>>(hidden, hn, NN);
  gemm128<0,0,1><<<gN, 256, 0, stream>>>(hn, wnd1T, bnd1, 1.f, NN, 128, x1b, nullptr, nullptr, 0.f);
  gemm128<0,3,0><<<gN, 256, 0, stream>>>(x1b, wnd2T, bnd2, 1.f, NN, 128, nullptr, out_node, x, 0.01f);

  // ---- edge decoder (in place on ea == out_edge region, all f32) ----
  ln_kernel<float,float><<<(EE+3)/4, 256, 0, stream>>>(ea, ea, EE);
  gemm128<1,1,1><<<gE, 256, 0, stream>>>(ea, wed1T, bed1, 1.f, EE, 128, nullptr, ea, nullptr, 0.f);
  gemm128<1,3,0><<<gE, 256, 0, stream>>>(ea, wed2T, bed2, 1.f, EE, 128, nullptr, out_edge, eatt, 0.01f);
}

// Round 4
// 1923.450 us; speedup vs baseline: 1.1664x; 1.1664x over previous
//
#include <hip/hip_runtime.h>
#include <cstdint>
#include <cstddef>

typedef __attribute__((ext_vector_type(8))) short short8x;
typedef __attribute__((ext_vector_type(4))) float f32x4;

static constexpr int NN = 20000;
static constexpr int EE = 640000;
static constexpr int NT_E = EE / 128;    // 5000 edge row-tiles
static constexpr int NPAIR = NT_E / 2;   // 2500 tile-pairs

#define DEVI __device__ __forceinline__

DEVI float b2f(uint16_t u){ union{uint32_t i; float f;} x; x.i = (uint32_t)u<<16; return x.f; }
DEVI uint16_t f2b(float f){ union{float f; uint32_t i;} x; x.f=f; uint32_t i=x.i;
  return (uint16_t)((i + 0x7FFFu + ((i>>16)&1u))>>16); }
DEVI float silu_f(float v){ return v / (1.f + __expf(-v)); }

DEVI uint4 pack8(float4 a, float4 b){
  union{uint16_t u[8]; uint4 q;} pk;
  pk.u[0]=f2b(a.x); pk.u[1]=f2b(a.y); pk.u[2]=f2b(a.z); pk.u[3]=f2b(a.w);
  pk.u[4]=f2b(b.x); pk.u[5]=f2b(b.y); pk.u[6]=f2b(b.z); pk.u[7]=f2b(b.w);
  return pk.q;
}

// =============== node-size MFMA GEMM (non-persistent) ===============
// C[M,128] = epi( A[M,K] @ W[K,128] + bias*bias_scale )
// AF32: A is f32 (else bf16). LNA: apply row-LayerNorm during staging (needs AF32,K=128).
// EPI: 0=store bf16, 1=store f32, 2=outf += v, 3=outf = resid + rs*v
template<int AF32, int LNA, int EPI, int SILU>
__global__ __launch_bounds__(256) void gemm_node(
    const void* Ap, const uint16_t* __restrict__ Wt,
    const float* __restrict__ bias, float bias_scale,
    int M, int K,
    uint16_t* outb, float* outf,
    const float* __restrict__ resid, float resid_scale)
{
  __shared__ uint16_t Als[128*136];
  __shared__ uint16_t Wls[128*136];
  const int t = threadIdx.x;
  const int row0 = blockIdx.x * 128;
  const int w = t >> 6, l = t & 63;
  const int lr = l & 15, lk = (l>>4)*8;

  f32x4 acc[2][8];
#pragma unroll
  for (int a=0;a<2;a++)
#pragma unroll
    for(int b=0;b<8;b++) acc[a][b] = (f32x4){0.f,0.f,0.f,0.f};

  for (int kc = 0; kc < K; kc += 128){
#pragma unroll
    for (int i=0;i<8;i++){                  // stage A tile 128x128 -> bf16 LDS
      int c = t + i*256;
      int r = c >> 4, k8 = (c & 15)*8;
      int gr = row0 + r;
      if (AF32){
        float4 a = {0.f,0.f,0.f,0.f}, b = {0.f,0.f,0.f,0.f};
        if (gr < M){
          const float* Af = (const float*)Ap + (size_t)gr*K + kc + k8;
          a = *(const float4*)Af;
          b = *(const float4*)(Af + 4);
        }
        if (LNA){
          float s = a.x+a.y+a.z+a.w + b.x+b.y+b.z+b.w;
          float q = a.x*a.x+a.y*a.y+a.z*a.z+a.w*a.w + b.x*b.x+b.y*b.y+b.z*b.z+b.w*b.w;
#pragma unroll
          for (int d=1; d<16; d<<=1){ s += __shfl_xor(s,d); q += __shfl_xor(q,d); }
          float m = s * 0.0078125f;
          float rstd = rsqrtf(fmaxf(q*0.0078125f - m*m, 0.f) + 1e-5f);
          a.x=(a.x-m)*rstd; a.y=(a.y-m)*rstd; a.z=(a.z-m)*rstd; a.w=(a.w-m)*rstd;
          b.x=(b.x-m)*rstd; b.y=(b.y-m)*rstd; b.z=(b.z-m)*rstd; b.w=(b.w-m)*rstd;
        }
        *(uint4*)(&Als[r*136 + k8]) = pack8(a, b);
      } else {
        uint4 v = {0u,0u,0u,0u};
        if (gr < M) v = *(const uint4*)((const uint16_t*)Ap + (size_t)gr*K + kc + k8);
        *(uint4*)(&Als[r*136 + k8]) = v;
      }
    }
#pragma unroll
    for (int i=0;i<8;i++){                  // stage Wt tile 128x128 (bf16)
      int c = t + i*256;
      int r = c >> 4, k8 = (c & 15)*8;
      uint4 v = *(const uint4*)(Wt + (size_t)r*K + kc + k8);
      *(uint4*)(&Wls[r*136 + k8]) = v;
    }
    __syncthreads();
#pragma unroll
    for (int kt=0; kt<4; ++kt){
      int kb = kt*32 + lk;
      short8x bfr[8];
#pragma unroll
      for (int c16=0;c16<8;c16++) bfr[c16] = *(const short8x*)(&Wls[(c16*16+lr)*136 + kb]);
#pragma unroll
      for (int r16=0;r16<2;r16++){
        short8x afr = *(const short8x*)(&Als[(w*32 + r16*16 + lr)*136 + kb]);
#pragma unroll
        for (int c16=0;c16<8;c16++)
          acc[r16][c16] = __builtin_amdgcn_mfma_f32_16x16x32_bf16(afr, bfr[c16], acc[r16][c16], 0,0,0);
      }
    }
    __syncthreads();
  }

  float bb[8];
#pragma unroll
  for (int c16=0;c16<8;c16++) bb[c16] = bias[c16*16+lr] * bias_scale;
#pragma unroll
  for (int r16=0;r16<2;r16++){
#pragma unroll
    for (int j=0;j<4;j++){
      int row = row0 + w*32 + r16*16 + (l>>4)*4 + j;
      if (row >= M) continue;
#pragma unroll
      for (int c16=0;c16<8;c16++){
        int col = c16*16 + lr;
        float v = acc[r16][c16][j] + bb[c16];
        if (SILU) v = silu_f(v);
        size_t o = (size_t)row*128 + col;
        if (EPI==0)      outb[o] = f2b(v);
        else if (EPI==1) outf[o] = v;
        else if (EPI==2) outf[o] += v;
        else             outf[o] = resid[o] + resid_scale*v;
      }
    }
  }
}

// =============== persistent edge encoder: ea = eatt @ We + be ===============
__global__ __launch_bounds__(256, 2) void enc_edge(
    const float* __restrict__ A, const uint16_t* __restrict__ Wt,
    const float* __restrict__ bias, float* __restrict__ outf)
{
  __shared__ uint16_t Als[128*136];
  __shared__ uint16_t Wls[128*136];
  const int t = threadIdx.x;
  const int w = t >> 6, l = t & 63;
  const int lr = l & 15, lk = (l>>4)*8;

#pragma unroll
  for (int i=0;i<8;i++){                    // stage W once
    int c = t + i*256;
    int r = c >> 4, k8 = (c & 15)*8;
    *(uint4*)(&Wls[r*136 + k8]) = *(const uint4*)(Wt + (size_t)r*128 + k8);
  }
  float bb[8];
#pragma unroll
  for (int c16=0;c16<8;c16++) bb[c16] = bias[c16*16+lr];

  int tile = blockIdx.x;
  float4 va[16];
#pragma unroll
  for (int i=0;i<16;i++) va[i] = (float4){0.f,0.f,0.f,0.f};
  if (tile < NT_E){
#pragma unroll
    for (int i=0;i<8;i++){
      int c = t + i*256; int r = c>>4, k8 = (c&15)*8;
      const float* Af = A + ((size_t)tile*128 + r)*128 + k8;
      va[2*i] = *(const float4*)Af; va[2*i+1] = *(const float4*)(Af + 4);
    }
  }
  while (tile < NT_E){
#pragma unroll
    for (int i=0;i<8;i++){                  // convert -> LDS (waits on loads)
      int c = t + i*256; int r = c>>4, k8 = (c&15)*8;
      *(uint4*)(&Als[r*136 + k8]) = pack8(va[2*i], va[2*i+1]);
    }
    int next = tile + (int)gridDim.x;
    if (next < NT_E){                       // prefetch next tile into regs
#pragma unroll
      for (int i=0;i<8;i++){
        int c = t + i*256; int r = c>>4, k8 = (c&15)*8;
        const float* Af = A + ((size_t)next*128 + r)*128 + k8;
        va[2*i] = *(const float4*)Af; va[2*i+1] = *(const float4*)(Af + 4);
      }
    }
    __syncthreads();
    f32x4 acc[2][8];
#pragma unroll
    for (int a=0;a<2;a++)
#pragma unroll
      for(int b=0;b<8;b++) acc[a][b] = (f32x4){0.f,0.f,0.f,0.f};
#pragma unroll
    for (int kt=0; kt<4; ++kt){
      int kb = kt*32 + lk;
      short8x bfr[8];
#pragma unroll
      for (int c16=0;c16<8;c16++) bfr[c16] = *(const short8x*)(&Wls[(c16*16+lr)*136 + kb]);
#pragma unroll
      for (int r16=0;r16<2;r16++){
        short8x afr = *(const short8x*)(&Als[(w*32 + r16*16 + lr)*136 + kb]);
#pragma unroll
        for (int c16=0;c16<8;c16++)
          acc[r16][c16] = __builtin_amdgcn_mfma_f32_16x16x32_bf16(afr, bfr[c16], acc[r16][c16], 0,0,0);
      }
    }
#pragma unroll
    for (int r16=0;r16<2;r16++)
#pragma unroll
      for (int j=0;j<4;j++){
        size_t row = (size_t)tile*128 + w*32 + r16*16 + (l>>4)*4 + j;
#pragma unroll
        for (int c16=0;c16<8;c16++)
          outf[row*128 + c16*16 + lr] = acc[r16][c16][j] + bb[c16];
      }
    __syncthreads();
    tile = next;
  }
}

// ====== persistent fused edge decoder: out = eatt + 0.01*(silu(LN(ea)@W1+b1)@W2+b2) ======
// 512 threads: waves 0-3 on tile pr*2, waves 4-7 on tile pr*2+1. In-place safe
// (outf==ea region): each block reads its own pair's rows into LDS before writing them.
__global__ __launch_bounds__(512) void dec_edge(
    const float* __restrict__ ea, const float* __restrict__ eatt,
    const uint16_t* __restrict__ W1t, const uint16_t* __restrict__ W2t,
    const float* __restrict__ b1, const float* __restrict__ b2,
    float* __restrict__ outf)
{
  __shared__ uint16_t Als[2][128*136];
  __shared__ uint16_t W1ls[128*136];
  __shared__ uint16_t W2ls[128*136];
  const int t = threadIdx.x;
  const int half = t >> 8, th = t & 255;       // staging role
  const int w = t >> 6, l = t & 63;
  const int lr = l & 15, lk = (l>>4)*8;
  const int tsel = w >> 2, wloc = w & 3;

#pragma unroll
  for (int i=0;i<4;i++){                       // stage W1,W2 once
    int c = t + i*512;
    int r = c >> 4, k8 = (c & 15)*8;
    *(uint4*)(&W1ls[r*136 + k8]) = *(const uint4*)(W1t + (size_t)r*128 + k8);
    *(uint4*)(&W2ls[r*136 + k8]) = *(const uint4*)(W2t + (size_t)r*128 + k8);
  }
  float bb1[8], bb2[8];
#pragma unroll
  for (int c16=0;c16<8;c16++){ bb1[c16] = b1[c16*16+lr]; bb2[c16] = b2[c16*16+lr]; }

  int pr = blockIdx.x;
  float4 va[16];
#pragma unroll
  for (int i=0;i<16;i++) va[i] = (float4){0.f,0.f,0.f,0.f};
  if (pr < NPAIR){
#pragma unroll
    for (int i=0;i<8;i++){
      int c = th + i*256; int r = c>>4, k8 = (c&15)*8;
      const float* Af = ea + ((size_t)pr*256 + half*128 + r)*128 + k8;
      va[2*i] = *(const float4*)Af; va[2*i+1] = *(const float4*)(Af + 4);
    }
  }
  while (pr < NPAIR){
#pragma unroll
    for (int i=0;i<8;i++){                     // LN + convert -> LDS
      int c = th + i*256; int r = c>>4, k8 = (c&15)*8;
      float4 a = va[2*i], b = va[2*i+1];
      float s = a.x+a.y+a.z+a.w + b.x+b.y+b.z+b.w;
      float q = a.x*a.x+a.y*a.y+a.z*a.z+a.w*a.w + b.x*b.x+b.y*b.y+b.z*b.z+b.w*b.w;
#pragma unroll
      for (int d=1; d<16; d<<=1){ s += __shfl_xor(s,d); q += __shfl_xor(q,d); }
      float m = s * 0.0078125f;
      float rstd = rsqrtf(fmaxf(q*0.0078125f - m*m, 0.f) + 1e-5f);
      a.x=(a.x-m)*rstd; a.y=(a.y-m)*rstd; a.z=(a.z-m)*rstd; a.w=(a.w-m)*rstd;
      b.x=(b.x-m)*rstd; b.y=(b.y-m)*rstd; b.z=(b.z-m)*rstd; b.w=(b.w-m)*rstd;
      *(uint4*)(&Als[half][r*136 + k8]) = pack8(a, b);
    }
    int nx = pr + (int)gridDim.x;
    if (nx < NPAIR){                           // prefetch next pair into regs
#pragma unroll
      for (int i=0;i<8;i++){
        int c = th + i*256; int r = c>>4, k8 = (c&15)*8;
        const float* Af = ea + ((size_t)nx*256 + half*128 + r)*128 + k8;
        va[2*i] = *(const float4*)Af; va[2*i+1] = *(const float4*)(Af + 4);
      }
    }
    __syncthreads();

    f32x4 acc[2][8];
#pragma unroll
    for (int a=0;a<2;a++)
#pragma unroll
      for(int b=0;b<8;b++) acc[a][b] = (f32x4){0.f,0.f,0.f,0.f};
#pragma unroll
    for (int kt=0; kt<4; ++kt){                // GEMM1: LN(ea) @ W1
      int kb = kt*32 + lk;
      short8x bfr[8];
#pragma unroll
      for (int c16=0;c16<8;c16++) bfr[c16] = *(const short8x*)(&W1ls[(c16*16+lr)*136 + kb]);
#pragma unroll
      for (int r16=0;r16<2;r16++){
        short8x afr = *(const short8x*)(&Als[tsel][(wloc*32 + r16*16 + lr)*136 + kb]);
#pragma unroll
        for (int c16=0;c16<8;c16++)
          acc[r16][c16] = __builtin_amdgcn_mfma_f32_16x16x32_bf16(afr, bfr[c16], acc[r16][c16], 0,0,0);
      }
    }
    // silu + bias -> tmp bf16 back into own 32-row stripe of Als[tsel]
    // (each wave reads/writes only its own stripe -> no barrier needed)
#pragma unroll
    for (int r16=0;r16<2;r16++)
#pragma unroll
      for (int c16=0;c16<8;c16++)
#pragma unroll
        for (int j=0;j<4;j++){
          int rloc = wloc*32 + r16*16 + (l>>4)*4 + j;
          Als[tsel][rloc*136 + c16*16 + lr] = f2b(silu_f(acc[r16][c16][j] + bb1[c16]));
        }
    f32x4 acc2[2][8];
#pragma unroll
    for (int a=0;a<2;a++)
#pragma unroll
      for(int b=0;b<8;b++) acc2[a][b] = (f32x4){0.f,0.f,0.f,0.f};
#pragma unroll
    for (int kt=0; kt<4; ++kt){                // GEMM2: tmp @ W2
      int kb = kt*32 + lk;
      short8x bfr[8];
#pragma unroll
      for (int c16=0;c16<8;c16++) bfr[c16] = *(const short8x*)(&W2ls[(c16*16+lr)*136 + kb]);
#pragma unroll
      for (int r16=0;r16<2;r16++){
        short8x afr = *(const short8x*)(&Als[tsel][(wloc*32 + r16*16 + lr)*136 + kb]);
#pragma unroll
        for (int c16=0;c16<8;c16++)
          acc2[r16][c16] = __builtin_amdgcn_mfma_f32_16x16x32_bf16(afr, bfr[c16], acc2[r16][c16], 0,0,0);
      }
    }
#pragma unroll
    for (int r16=0;r16<2;r16++)
#pragma unroll
      for (int j=0;j<4;j++){
        size_t row = (size_t)pr*256 + tsel*128 + wloc*32 + r16*16 + (l>>4)*4 + j;
#pragma unroll
        for (int c16=0;c16<8;c16++){
          size_t o = row*128 + c16*16 + lr;
          outf[o] = eatt[o] + 0.01f*(acc2[r16][c16][j] + bb2[c16]);
        }
      }
    __syncthreads();
    pr = nx;
  }
}

// ---------------- per-node gather aggregation ----------------
template<int INV, int EUPD, int ACCUM>
__global__ __launch_bounds__(128) void agg_kernel(
    const float* ea, float* ea_out,
    const uint16_t* __restrict__ x1, const uint16_t* __restrict__ z,
    const uint16_t* __restrict__ h3, const uint16_t* __restrict__ h4,
    const int* __restrict__ eids, const int* __restrict__ ptr,
    const int* __restrict__ other, uint16_t* stats)
{
  __shared__ int se[128];
  __shared__ int so[128];
  int i = blockIdx.x, f = threadIdx.x;
  size_t ib = (size_t)i*128 + f;
  float zi = b2f(z[ib]);
  float h3i = 0.f, h4i = 0.f;
  if (EUPD){ h3i = b2f(h3[ib]); h4i = b2f(h4[ib]); }
  int beg = ptr[i], end = ptr[i+1];
  float s=0.f, s2=0.f, mx=-3.4e38f, mn=3.4e38f;
  for (int jb = beg; jb < end; jb += 128){
    int cn = min(128, end - jb);
    if (f < cn){ int e = eids[jb+f]; se[f] = e; so[f] = other[e]; }
    __syncthreads();
#pragma unroll 4
    for (int jj = 0; jj < cn; ++jj){
      int e = se[jj], o = so[jj];
      float x1v = b2f(x1[(size_t)o*128 + f]);
      float eav = ea[(size_t)e*128 + f];
      float m = zi * x1v * eav;
      if (INV){ if (f >= 64) m = -m; }
      s += m; s2 += m*m; mx = fmaxf(mx, m); mn = fminf(mn, m);
      if (EUPD){
        float h3o = b2f(h3[(size_t)o*128 + f]);
        float h4o = b2f(h4[(size_t)o*128 + f]);
        ea_out[(size_t)e*128 + f] = eav * (1.f + h3o*h4i + h3i*h4o);
      }
    }
    __syncthreads();
  }
  int cnt = end - beg;
  float dn = cnt > 0 ? 1.f/(float)cnt : 1.f;
  float mean = s*dn, m2 = s2*dn;
  float sd = sqrtf(fmaxf(m2 - mean*mean, 0.f) + 1e-5f);
  if (cnt == 0){ mx = 0.f; mn = 0.f; }
  size_t o0 = (size_t)i*512 + f;
  if (ACCUM){
    stats[o0    ] = f2b(b2f(stats[o0    ]) + mean);
    stats[o0+128] = f2b(b2f(stats[o0+128]) + sd);
    stats[o0+256] = f2b(b2f(stats[o0+256]) + mx);
    stats[o0+384] = f2b(b2f(stats[o0+384]) + mn);
  } else {
    stats[o0]=f2b(mean); stats[o0+128]=f2b(sd); stats[o0+256]=f2b(mx); stats[o0+384]=f2b(mn);
  }
}

// ---------------- CSR build ----------------
__global__ void count_deg(const int* __restrict__ ei, int* cnt_src, int* cnt_dst){
  int e = blockIdx.x*256 + threadIdx.x;
  if (e < EE){
    atomicAdd(&cnt_src[ei[e]], 1);
    atomicAdd(&cnt_dst[ei[EE+e]], 1);
  }
}

__global__ __launch_bounds__(1024) void scan_excl(const int* __restrict__ cnt, int* ptr, int n){
  __shared__ int buf[1024];
  __shared__ int carry;
  int t = threadIdx.x;
  if (t==0) carry = 0;
  __syncthreads();
  for (int base=0; base<n; base+=1024){
    int v = (base+t < n) ? cnt[base+t] : 0;
    int acc = v;
    buf[t] = acc;
    __syncthreads();
    for (int s=1; s<1024; s<<=1){
      int add = (t>=s) ? buf[t-s] : 0;
      __syncthreads();
      acc += add;
      buf[t] = acc;
      __syncthreads();
    }
    if (base+t < n) ptr[base+t] = carry + acc - v;
    int tot = buf[1023];
    __syncthreads();
    if (t==0) carry += tot;
    __syncthreads();
  }
  if (t==0) ptr[n] = carry;
}

__global__ void init_cursor(const int* p1, int* c1, const int* p2, int* c2, int n){
  int i = blockIdx.x*256 + threadIdx.x;
  if (i < n){ c1[i] = p1[i]; c2[i] = p2[i]; }
}

__global__ void scatter_edges(const int* __restrict__ ei, int* cur_src, int* cur_dst,
                              int* eid_src, int* eid_dst){
  int e = blockIdx.x*256 + threadIdx.x;
  if (e < EE){
    int s = ei[e], d = ei[EE+e];
    eid_src[atomicAdd(&cur_src[s],1)] = e;
    eid_dst[atomicAdd(&cur_dst[d],1)] = e;
  }
}

// ------- weight transpose+cast: W[m][k][c] (f32) -> Wt[m][c][k] (bf16) -------
__global__ void transpose_w(const float* __restrict__ W, uint16_t* __restrict__ Wt,
                            int K, int total){
  int idx = blockIdx.x*256 + threadIdx.x;
  if (idx < total){
    int per = K*128;
    int m = idx / per, r = idx - m*per;
    int k = r >> 7, c = r & 127;
    Wt[(size_t)m*per + (size_t)c*K + k] = f2b(W[idx]);
  }
}

extern "C" void kernel_launch(void* const* d_in, const int* in_sizes, int n_in,
                              void* d_out, int out_size, void* d_ws, size_t ws_size,
                              hipStream_t stream)
{
  const float* x    = (const float*)d_in[0];
  const float* eatt = (const float*)d_in[1];
  const float* Wn   = (const float*)d_in[2];
  const float* bn   = (const float*)d_in[3];
  const float* We   = (const float*)d_in[4];
  const float* be   = (const float*)d_in[5];
  const float* W1   = (const float*)d_in[6];
  const float* b1   = (const float*)d_in[7];
  const float* W2   = (const float*)d_in[8];
  const float* b2   = (const float*)d_in[9];
  const float* W3   = (const float*)d_in[10];
  const float* b3   = (const float*)d_in[11];
  const float* W4   = (const float*)d_in[12];
  const float* b4   = (const float*)d_in[13];
  const float* Wd   = (const float*)d_in[14];
  const float* bd   = (const float*)d_in[15];
  const float* Wnd1 = (const float*)d_in[16];
  const float* bnd1 = (const float*)d_in[17];
  const float* Wnd2 = (const float*)d_in[18];
  const float* bnd2 = (const float*)d_in[19];
  const float* Wed1 = (const float*)d_in[20];
  const float* bed1 = (const float*)d_in[21];
  const float* Wed2 = (const float*)d_in[22];
  const float* bed2 = (const float*)d_in[23];
  const int* ei     = (const int*)d_in[24];

  float* out_node = (float*)d_out;
  float* out_edge = out_node + (size_t)NN*128;
  float* ea = out_edge;   // ea lives (f32) in out_edge region; fully rewritten each call

  char* p = (char*)d_ws;
  auto alloc = [&](size_t bytes)->char*{
    char* r = p; p += (bytes + 255) & ~(size_t)255; return r; };

  float*    hidden = (float*)   alloc((size_t)NN*128*4);
  uint16_t* x1b    = (uint16_t*)alloc((size_t)NN*128*2);
  uint16_t* zb     = (uint16_t*)alloc((size_t)NN*128*2);
  uint16_t* h3b    = (uint16_t*)alloc((size_t)NN*128*2);
  uint16_t* h4b    = (uint16_t*)alloc((size_t)NN*128*2);
  uint16_t* stats  = (uint16_t*)alloc((size_t)NN*512*2);
  int* cnt_src = (int*)alloc((size_t)NN*4);
  int* cnt_dst = (int*)alloc((size_t)NN*4);
  int* ptr_src = (int*)alloc((size_t)(NN+1)*4);
  int* ptr_dst = (int*)alloc((size_t)(NN+1)*4);
  int* cur_src = (int*)alloc((size_t)NN*4);
  int* cur_dst = (int*)alloc((size_t)NN*4);
  int* eid_src = (int*)alloc((size_t)EE*4);
  int* eid_dst = (int*)alloc((size_t)EE*4);
  uint16_t* WT = (uint16_t*)alloc((size_t)491520*2);

  uint16_t* wnT   = WT;
  uint16_t* weT   = WT + 16384;
  uint16_t* w1T   = WT + 32768;
  uint16_t* w2T   = WT + 81920;
  uint16_t* w3T   = WT + 131072;
  uint16_t* w4T   = WT + 180224;
  uint16_t* wdT   = WT + 229376;
  uint16_t* wnd1T = WT + 425984;
  uint16_t* wnd2T = WT + 442368;
  uint16_t* wed1T = WT + 458752;
  uint16_t* wed2T = WT + 475136;

  // ---- CSR build ----
  hipMemsetAsync(cnt_src, 0, (size_t)NN*4, stream);
  hipMemsetAsync(cnt_dst, 0, (size_t)NN*4, stream);
  count_deg<<<(EE+255)/256, 256, 0, stream>>>(ei, cnt_src, cnt_dst);
  scan_excl<<<1, 1024, 0, stream>>>(cnt_src, ptr_src, NN);
  scan_excl<<<1, 1024, 0, stream>>>(cnt_dst, ptr_dst, NN);
  init_cursor<<<(NN+255)/256, 256, 0, stream>>>(ptr_src, cur_src, ptr_dst, cur_dst, NN);
  scatter_edges<<<(EE+255)/256, 256, 0, stream>>>(ei, cur_src, cur_dst, eid_src, eid_dst);

  // ---- transpose+cast weights ----
  transpose_w<<<64, 256, 0, stream>>>(Wn, wnT, 128, 16384);
  transpose_w<<<64, 256, 0, stream>>>(We, weT, 128, 16384);
  transpose_w<<<192, 256, 0, stream>>>(W1, w1T, 128, 49152);
  transpose_w<<<192, 256, 0, stream>>>(W2, w2T, 128, 49152);
  transpose_w<<<192, 256, 0, stream>>>(W3, w3T, 128, 49152);
  transpose_w<<<192, 256, 0, stream>>>(W4, w4T, 128, 49152);
  transpose_w<<<768, 256, 0, stream>>>(Wd, wdT, 512, 196608);
  transpose_w<<<64, 256, 0, stream>>>(Wnd1, wnd1T, 128, 16384);
  transpose_w<<<64, 256, 0, stream>>>(Wnd2, wnd2T, 128, 16384);
  transpose_w<<<64, 256, 0, stream>>>(Wed1, wed1T, 128, 16384);
  transpose_w<<<64, 256, 0, stream>>>(Wed2, wed2T, 128, 16384);

  const int gN = (NN+127)/128;

  // ---- encoders ----
  gemm_node<1,0,1,0><<<gN, 256, 0, stream>>>(x, wnT, bn, 1.f, NN, 128, nullptr, hidden, nullptr, 0.f);
  enc_edge<<<512, 256, 0, stream>>>(eatt, weT, be, ea);

  // ---- layers ----
  for (int lyr = 0; lyr < 3; ++lyr){
    const uint16_t* w1l = w1T + lyr*16384;
    const uint16_t* w2l = w2T + lyr*16384;
    const uint16_t* w3l = w3T + lyr*16384;
    const uint16_t* w4l = w4T + lyr*16384;
    const uint16_t* wdl = wdT + lyr*65536;
    const float* b1l = b1 + lyr*128;
    const float* b2l = b2 + lyr*128;
    const float* b3l = b3 + lyr*128;
    const float* b4l = b4 + lyr*128;
    const float* bdl = bd + lyr*128;

    // LN fused into staging (LNA=1) of the four projections of hidden
    gemm_node<1,1,0,1><<<gN, 256, 0, stream>>>(hidden, w1l, b1l, 1.f, NN, 128, x1b, nullptr, nullptr, 0.f);
    gemm_node<1,1,0,1><<<gN, 256, 0, stream>>>(hidden, w2l, b2l, 1.f, NN, 128, zb,  nullptr, nullptr, 0.f);
    gemm_node<1,1,0,1><<<gN, 256, 0, stream>>>(hidden, w3l, b3l, 1.f, NN, 128, h3b, nullptr, nullptr, 0.f);
    gemm_node<1,1,0,1><<<gN, 256, 0, stream>>>(hidden, w4l, b4l, 1.f, NN, 128, h4b, nullptr, nullptr, 0.f);

    // src-direction aggregation (with inv sign), writes stats
    agg_kernel<1,0,0><<<NN, 128, 0, stream>>>(ea, nullptr, x1b, zb, nullptr, nullptr,
                                              eid_src, ptr_src, ei + EE, stats);
    // dst-direction aggregation, accumulates stats, fused in-place ea update
    agg_kernel<0,1,1><<<NN, 128, 0, stream>>>(ea, ea, x1b, zb, h3b, h4b,
                                              eid_dst, ptr_dst, ei, stats);
    // hidden += stats @ Wd + 2*bd
    gemm_node<0,0,2,0><<<gN, 256, 0, stream>>>(stats, wdl, bdl, 2.f, NN, 512, nullptr, hidden, nullptr, 0.f);
  }

  // ---- node decoder (LN fused into first GEMM) ----
  gemm_node<1,1,0,1><<<gN, 256, 0, stream>>>(hidden, wnd1T, bnd1, 1.f, NN, 128, x1b, nullptr, nullptr, 0.f);
  gemm_node<0,0,3,0><<<gN, 256, 0, stream>>>(x1b, wnd2T, bnd2, 1.f, NN, 128, nullptr, out_node, x, 0.01f);

  // ---- edge decoder: fused LN + GEMM1(silu) + GEMM2 + residual, in place ----
  dec_edge<<<256, 512, 0, stream>>>(ea, eatt, wed1T, wed2T, bed1, bed2, out_edge);
}

// Round 5
// 1704.812 us; speedup vs baseline: 1.3159x; 1.1282x over previous
//
#include <hip/hip_runtime.h>
#include <cstdint>
#include <cstddef>

typedef __attribute__((ext_vector_type(8))) short short8x;
typedef __attribute__((ext_vector_type(4))) float f32x4;

static constexpr int NN = 20000;
static constexpr int EE = 640000;
static constexpr int NT_E = EE / 128;    // 5000 edge row-tiles
static constexpr int NPAIR = NT_E / 2;   // 2500 tile-pairs

#define DEVI __device__ __forceinline__

DEVI float b2f(uint16_t u){ union{uint32_t i; float f;} x; x.i = (uint32_t)u<<16; return x.f; }
DEVI uint16_t f2b(float f){ union{float f; uint32_t i;} x; x.f=f; uint32_t i=x.i;
  return (uint16_t)((i + 0x7FFFu + ((i>>16)&1u))>>16); }
DEVI float silu_f(float v){ return v / (1.f + __expf(-v)); }

DEVI uint4 pack8(float4 a, float4 b){
  union{uint16_t u[8]; uint4 q;} pk;
  pk.u[0]=f2b(a.x); pk.u[1]=f2b(a.y); pk.u[2]=f2b(a.z); pk.u[3]=f2b(a.w);
  pk.u[4]=f2b(b.x); pk.u[5]=f2b(b.y); pk.u[6]=f2b(b.z); pk.u[7]=f2b(b.w);
  return pk.q;
}
DEVI uint2 pack4(float4 a){
  union{uint16_t u[4]; uint2 q;} pk;
  pk.u[0]=f2b(a.x); pk.u[1]=f2b(a.y); pk.u[2]=f2b(a.z); pk.u[3]=f2b(a.w);
  return pk.q;
}
DEVI float4 unpk4(uint2 v){
  return (float4){ b2f((uint16_t)(v.x & 0xFFFFu)), b2f((uint16_t)(v.x >> 16)),
                   b2f((uint16_t)(v.y & 0xFFFFu)), b2f((uint16_t)(v.y >> 16)) };
}

// LN a row of 128 spread over 16-lane groups holding 8 consecutive elems each
DEVI void ln8(float4& a, float4& b){
  float s = a.x+a.y+a.z+a.w + b.x+b.y+b.z+b.w;
  float q = a.x*a.x+a.y*a.y+a.z*a.z+a.w*a.w + b.x*b.x+b.y*b.y+b.z*b.z+b.w*b.w;
#pragma unroll
  for (int d=1; d<16; d<<=1){ s += __shfl_xor(s,d); q += __shfl_xor(q,d); }
  float m = s * 0.0078125f;
  float rstd = rsqrtf(fmaxf(q*0.0078125f - m*m, 0.f) + 1e-5f);
  a.x=(a.x-m)*rstd; a.y=(a.y-m)*rstd; a.z=(a.z-m)*rstd; a.w=(a.w-m)*rstd;
  b.x=(b.x-m)*rstd; b.y=(b.y-m)*rstd; b.z=(b.z-m)*rstd; b.w=(b.w-m)*rstd;
}

// =============== node-size MFMA GEMM (swapped-C epilogue) ===============
// C[M,128] = epi( A[M,K] @ W[K,128] + bias*bias_scale )
// EPI: 0=store bf16 (uint2), 1=store f32 (float4), 2=outf += v, 3=outf = resid + rs*v
template<int AF32, int LNA, int EPI, int SILU>
__global__ __launch_bounds__(256) void gemm_node(
    const void* Ap, const uint16_t* __restrict__ Wt,
    const float* __restrict__ bias, float bias_scale,
    int M, int K,
    uint16_t* outb, float* outf,
    const float* __restrict__ resid, float resid_scale)
{
  __shared__ uint16_t Als[128*136];
  __shared__ uint16_t Wls[128*136];
  const int t = threadIdx.x;
  const int row0 = blockIdx.x * 128;
  const int w = t >> 6, l = t & 63;
  const int lr = l & 15, lk = (l>>4)*8;

  f32x4 acc[2][8];
#pragma unroll
  for (int a=0;a<2;a++)
#pragma unroll
    for(int b=0;b<8;b++) acc[a][b] = (f32x4){0.f,0.f,0.f,0.f};

  for (int kc = 0; kc < K; kc += 128){
#pragma unroll
    for (int i=0;i<8;i++){                  // stage A tile 128x128 -> bf16 LDS
      int c = t + i*256;
      int r = c >> 4, k8 = (c & 15)*8;
      int gr = row0 + r;
      if (AF32){
        float4 a = {0.f,0.f,0.f,0.f}, b = {0.f,0.f,0.f,0.f};
        if (gr < M){
          const float* Af = (const float*)Ap + (size_t)gr*K + kc + k8;
          a = *(const float4*)Af; b = *(const float4*)(Af + 4);
        }
        if (LNA) ln8(a, b);
        *(uint4*)(&Als[r*136 + k8]) = pack8(a, b);
      } else {
        uint4 v = {0u,0u,0u,0u};
        if (gr < M) v = *(const uint4*)((const uint16_t*)Ap + (size_t)gr*K + kc + k8);
        *(uint4*)(&Als[r*136 + k8]) = v;
      }
    }
#pragma unroll
    for (int i=0;i<8;i++){                  // stage Wt tile 128x128 (bf16)
      int c = t + i*256;
      int r = c >> 4, k8 = (c & 15)*8;
      *(uint4*)(&Wls[r*136 + k8]) = *(const uint4*)(Wt + (size_t)r*K + kc + k8);
    }
    __syncthreads();
#pragma unroll
    for (int kt=0; kt<4; ++kt){
      int kb = kt*32 + lk;
      short8x bfr[8];
#pragma unroll
      for (int c16=0;c16<8;c16++) bfr[c16] = *(const short8x*)(&Wls[(c16*16+lr)*136 + kb]);
#pragma unroll
      for (int r16=0;r16<2;r16++){
        short8x afr = *(const short8x*)(&Als[(w*32 + r16*16 + lr)*136 + kb]);
#pragma unroll
        for (int c16=0;c16<8;c16++)   // swapped: acc = W^T-frag x A-frag -> C^T layout
          acc[r16][c16] = __builtin_amdgcn_mfma_f32_16x16x32_bf16(bfr[c16], afr, acc[r16][c16], 0,0,0);
      }
    }
    __syncthreads();
  }

  float4 bbv[8];
#pragma unroll
  for (int c16=0;c16<8;c16++){
    float4 b4 = *(const float4*)(bias + c16*16 + (l>>4)*4);
    bbv[c16] = (float4){b4.x*bias_scale, b4.y*bias_scale, b4.z*bias_scale, b4.w*bias_scale};
  }
#pragma unroll
  for (int r16=0;r16<2;r16++){
    int row = row0 + w*32 + r16*16 + lr;
    if (row >= M) continue;
#pragma unroll
    for (int c16=0;c16<8;c16++){
      int colb = c16*16 + (l>>4)*4;
      float4 v = (float4){acc[r16][c16][0]+bbv[c16].x, acc[r16][c16][1]+bbv[c16].y,
                          acc[r16][c16][2]+bbv[c16].z, acc[r16][c16][3]+bbv[c16].w};
      if (SILU){ v.x=silu_f(v.x); v.y=silu_f(v.y); v.z=silu_f(v.z); v.w=silu_f(v.w); }
      size_t o = (size_t)row*128 + colb;
      if (EPI==0)      *(uint2*)(outb + o) = pack4(v);
      else if (EPI==1) *(float4*)(outf + o) = v;
      else if (EPI==2){ float4 old = *(const float4*)(outf + o);
        *(float4*)(outf + o) = (float4){old.x+v.x, old.y+v.y, old.z+v.z, old.w+v.w}; }
      else { float4 r = *(const float4*)(resid + o);
        *(float4*)(outf + o) = (float4){r.x+resid_scale*v.x, r.y+resid_scale*v.y,
                                        r.z+resid_scale*v.z, r.w+resid_scale*v.w}; }
    }
  }
}

// ======= fused 4-projection: outp[p] = silu(LN(hidden) @ Wp + bp), p=0..3 =======
__global__ __launch_bounds__(256) void proj4(
    const float* __restrict__ hidden, const uint16_t* __restrict__ Wt4,
    const float* __restrict__ b0p, const float* __restrict__ b1p,
    const float* __restrict__ b2p, const float* __restrict__ b3p,
    uint16_t* o0, uint16_t* o1, uint16_t* o2, uint16_t* o3, int M)
{
  __shared__ uint16_t Als[128*136];
  __shared__ uint16_t Wls[2][128*136];
  const int t = threadIdx.x;
  const int row0 = blockIdx.x * 128;
  const int w = t >> 6, l = t & 63;
  const int lr = l & 15, lk = (l>>4)*8;

#pragma unroll
  for (int i=0;i<8;i++){                    // stage A with LN
    int c = t + i*256;
    int r = c >> 4, k8 = (c & 15)*8;
    int gr = row0 + r;
    float4 a = {0.f,0.f,0.f,0.f}, b = {0.f,0.f,0.f,0.f};
    if (gr < M){
      const float* Af = hidden + (size_t)gr*128 + k8;
      a = *(const float4*)Af; b = *(const float4*)(Af + 4);
    }
    ln8(a, b);
    *(uint4*)(&Als[r*136 + k8]) = pack8(a, b);
  }
#pragma unroll
  for (int i=0;i<8;i++){                    // stage W0
    int c = t + i*256;
    int r = c >> 4, k8 = (c & 15)*8;
    *(uint4*)(&Wls[0][r*136 + k8]) = *(const uint4*)(Wt4 + (size_t)r*128 + k8);
  }
  __syncthreads();

#pragma unroll
  for (int p=0; p<4; ++p){
    if (p < 3){
#pragma unroll
      for (int i=0;i<8;i++){                // stage W(p+1) into other buffer
        int c = t + i*256;
        int r = c >> 4, k8 = (c & 15)*8;
        *(uint4*)(&Wls[(p+1)&1][r*136 + k8]) =
          *(const uint4*)(Wt4 + (size_t)(p+1)*16384 + (size_t)r*128 + k8);
      }
    }
    f32x4 acc[2][8];
#pragma unroll
    for (int a=0;a<2;a++)
#pragma unroll
      for(int b=0;b<8;b++) acc[a][b] = (f32x4){0.f,0.f,0.f,0.f};
#pragma unroll
    for (int kt=0; kt<4; ++kt){
      int kb = kt*32 + lk;
      short8x bfr[8];
#pragma unroll
      for (int c16=0;c16<8;c16++) bfr[c16] = *(const short8x*)(&Wls[p&1][(c16*16+lr)*136 + kb]);
#pragma unroll
      for (int r16=0;r16<2;r16++){
        short8x afr = *(const short8x*)(&Als[(w*32 + r16*16 + lr)*136 + kb]);
#pragma unroll
        for (int c16=0;c16<8;c16++)
          acc[r16][c16] = __builtin_amdgcn_mfma_f32_16x16x32_bf16(bfr[c16], afr, acc[r16][c16], 0,0,0);
      }
    }
    const float* bp = (p==0)?b0p:(p==1)?b1p:(p==2)?b2p:b3p;
    uint16_t* op = (p==0)?o0:(p==1)?o1:(p==2)?o2:o3;
#pragma unroll
    for (int r16=0;r16<2;r16++){
      int row = row0 + w*32 + r16*16 + lr;
      if (row >= M) continue;
#pragma unroll
      for (int c16=0;c16<8;c16++){
        int colb = c16*16 + (l>>4)*4;
        float4 b4 = *(const float4*)(bp + colb);
        float4 v = (float4){silu_f(acc[r16][c16][0]+b4.x), silu_f(acc[r16][c16][1]+b4.y),
                            silu_f(acc[r16][c16][2]+b4.z), silu_f(acc[r16][c16][3]+b4.w)};
        *(uint2*)(op + (size_t)row*128 + colb) = pack4(v);
      }
    }
    __syncthreads();
  }
}

// =============== persistent edge encoder: ea = eatt @ We + be (f32 out) ===============
__global__ __launch_bounds__(256, 2) void enc_edge(
    const float* __restrict__ A, const uint16_t* __restrict__ Wt,
    const float* __restrict__ bias, float* __restrict__ outf)
{
  __shared__ uint16_t Als[128*136];
  __shared__ uint16_t Wls[128*136];
  const int t = threadIdx.x;
  const int w = t >> 6, l = t & 63;
  const int lr = l & 15, lk = (l>>4)*8;

#pragma unroll
  for (int i=0;i<8;i++){
    int c = t + i*256;
    int r = c >> 4, k8 = (c & 15)*8;
    *(uint4*)(&Wls[r*136 + k8]) = *(const uint4*)(Wt + (size_t)r*128 + k8);
  }
  float4 bbv[8];
#pragma unroll
  for (int c16=0;c16<8;c16++) bbv[c16] = *(const float4*)(bias + c16*16 + (l>>4)*4);

  int tile = blockIdx.x;
  float4 va[16];
#pragma unroll
  for (int i=0;i<8;i++){
    int c = t + i*256; int r = c>>4, k8 = (c&15)*8;
    const float* Af = A + ((size_t)tile*128 + r)*128 + k8;
    va[2*i] = *(const float4*)Af; va[2*i+1] = *(const float4*)(Af + 4);
  }
  while (tile < NT_E){
#pragma unroll
    for (int i=0;i<8;i++){
      int c = t + i*256; int r = c>>4, k8 = (c&15)*8;
      *(uint4*)(&Als[r*136 + k8]) = pack8(va[2*i], va[2*i+1]);
    }
    int next = tile + (int)gridDim.x;
    if (next < NT_E){
#pragma unroll
      for (int i=0;i<8;i++){
        int c = t + i*256; int r = c>>4, k8 = (c&15)*8;
        const float* Af = A + ((size_t)next*128 + r)*128 + k8;
        va[2*i] = *(const float4*)Af; va[2*i+1] = *(const float4*)(Af + 4);
      }
    }
    __syncthreads();
    f32x4 acc[2][8];
#pragma unroll
    for (int a=0;a<2;a++)
#pragma unroll
      for(int b=0;b<8;b++) acc[a][b] = (f32x4){0.f,0.f,0.f,0.f};
#pragma unroll
    for (int kt=0; kt<4; ++kt){
      int kb = kt*32 + lk;
      short8x bfr[8];
#pragma unroll
      for (int c16=0;c16<8;c16++) bfr[c16] = *(const short8x*)(&Wls[(c16*16+lr)*136 + kb]);
#pragma unroll
      for (int r16=0;r16<2;r16++){
        short8x afr = *(const short8x*)(&Als[(w*32 + r16*16 + lr)*136 + kb]);
#pragma unroll
        for (int c16=0;c16<8;c16++)
          acc[r16][c16] = __builtin_amdgcn_mfma_f32_16x16x32_bf16(bfr[c16], afr, acc[r16][c16], 0,0,0);
      }
    }
#pragma unroll
    for (int r16=0;r16<2;r16++){
      size_t row = (size_t)tile*128 + w*32 + r16*16 + lr;
#pragma unroll
      for (int c16=0;c16<8;c16++){
        int colb = c16*16 + (l>>4)*4;
        *(float4*)(outf + row*128 + colb) =
          (float4){acc[r16][c16][0]+bbv[c16].x, acc[r16][c16][1]+bbv[c16].y,
                   acc[r16][c16][2]+bbv[c16].z, acc[r16][c16][3]+bbv[c16].w};
      }
    }
    __syncthreads();
    tile = next;
  }
}

// ====== persistent fused edge decoder: out = eatt + 0.01*(silu(LN(ea)@W1+b1)@W2+b2) ======
__global__ __launch_bounds__(512) void dec_edge(
    const float* __restrict__ ea, const float* __restrict__ eatt,
    const uint16_t* __restrict__ W1t, const uint16_t* __restrict__ W2t,
    const float* __restrict__ b1, const float* __restrict__ b2,
    float* __restrict__ outf)
{
  __shared__ uint16_t Als[2][128*136];
  __shared__ uint16_t W1ls[128*136];
  __shared__ uint16_t W2ls[128*136];
  const int t = threadIdx.x;
  const int half = t >> 8, th = t & 255;
  const int w = t >> 6, l = t & 63;
  const int lr = l & 15, lk = (l>>4)*8;
  const int tsel = w >> 2, wloc = w & 3;

#pragma unroll
  for (int i=0;i<4;i++){
    int c = t + i*512;
    int r = c >> 4, k8 = (c & 15)*8;
    *(uint4*)(&W1ls[r*136 + k8]) = *(const uint4*)(W1t + (size_t)r*128 + k8);
    *(uint4*)(&W2ls[r*136 + k8]) = *(const uint4*)(W2t + (size_t)r*128 + k8);
  }
  float bb1[8];
  float4 bb2v[8];
#pragma unroll
  for (int c16=0;c16<8;c16++){
    bb1[c16] = b1[c16*16+lr];
    bb2v[c16] = *(const float4*)(b2 + c16*16 + (l>>4)*4);
  }

  int pr = blockIdx.x;
  float4 va[16];   // ea staging (th-pattern)
  float4 vet[16];  // eatt in output-fragment pattern [r16*8+c16]
#pragma unroll
  for (int i=0;i<8;i++){
    int c = th + i*256; int r = c>>4, k8 = (c&15)*8;
    const float* Af = ea + ((size_t)pr*256 + half*128 + r)*128 + k8;
    va[2*i] = *(const float4*)Af; va[2*i+1] = *(const float4*)(Af + 4);
  }
#pragma unroll
  for (int r16=0;r16<2;r16++)
#pragma unroll
    for (int c16=0;c16<8;c16++){
      size_t row = (size_t)pr*256 + tsel*128 + wloc*32 + r16*16 + lr;
      vet[r16*8+c16] = *(const float4*)(eatt + row*128 + c16*16 + (l>>4)*4);
    }

  while (pr < NPAIR){
#pragma unroll
    for (int i=0;i<8;i++){                     // LN + convert -> LDS
      int c = th + i*256; int r = c>>4, k8 = (c&15)*8;
      float4 a = va[2*i], b = va[2*i+1];
      ln8(a, b);
      *(uint4*)(&Als[half][r*136 + k8]) = pack8(a, b);
    }
    int nx = pr + (int)gridDim.x;
    if (nx < NPAIR){                           // prefetch next ea pair
#pragma unroll
      for (int i=0;i<8;i++){
        int c = th + i*256; int r = c>>4, k8 = (c&15)*8;
        const float* Af = ea + ((size_t)nx*256 + half*128 + r)*128 + k8;
        va[2*i] = *(const float4*)Af; va[2*i+1] = *(const float4*)(Af + 4);
      }
    }
    __syncthreads();

    f32x4 acc[2][8];
#pragma unroll
    for (int a=0;a<2;a++)
#pragma unroll
      for(int b=0;b<8;b++) acc[a][b] = (f32x4){0.f,0.f,0.f,0.f};
#pragma unroll
    for (int kt=0; kt<4; ++kt){                // GEMM1 (original orientation)
      int kb = kt*32 + lk;
      short8x bfr[8];
#pragma unroll
      for (int c16=0;c16<8;c16++) bfr[c16] = *(const short8x*)(&W1ls[(c16*16+lr)*136 + kb]);
#pragma unroll
      for (int r16=0;r16<2;r16++){
        short8x afr = *(const short8x*)(&Als[tsel][(wloc*32 + r16*16 + lr)*136 + kb]);
#pragma unroll
        for (int c16=0;c16<8;c16++)
          acc[r16][c16] = __builtin_amdgcn_mfma_f32_16x16x32_bf16(afr, bfr[c16], acc[r16][c16], 0,0,0);
      }
    }
    // silu + bias -> bf16 tmp in own 32-row stripe (wave-local, no barrier)
#pragma unroll
    for (int r16=0;r16<2;r16++)
#pragma unroll
      for (int c16=0;c16<8;c16++)
#pragma unroll
        for (int j=0;j<4;j++){
          int rloc = wloc*32 + r16*16 + (l>>4)*4 + j;
          Als[tsel][rloc*136 + c16*16 + lr] = f2b(silu_f(acc[r16][c16][j] + bb1[c16]));
        }
    f32x4 acc2[2][8];
#pragma unroll
    for (int a=0;a<2;a++)
#pragma unroll
      for(int b=0;b<8;b++) acc2[a][b] = (f32x4){0.f,0.f,0.f,0.f};
#pragma unroll
    for (int kt=0; kt<4; ++kt){                // GEMM2 swapped -> C^T layout
      int kb = kt*32 + lk;
      short8x bfr[8];
#pragma unroll
      for (int c16=0;c16<8;c16++) bfr[c16] = *(const short8x*)(&W2ls[(c16*16+lr)*136 + kb]);
#pragma unroll
      for (int r16=0;r16<2;r16++){
        short8x afr = *(const short8x*)(&Als[tsel][(wloc*32 + r16*16 + lr)*136 + kb]);
#pragma unroll
        for (int c16=0;c16<8;c16++)
          acc2[r16][c16] = __builtin_amdgcn_mfma_f32_16x16x32_bf16(bfr[c16], afr, acc2[r16][c16], 0,0,0);
      }
    }
#pragma unroll
    for (int r16=0;r16<2;r16++){
      size_t row = (size_t)pr*256 + tsel*128 + wloc*32 + r16*16 + lr;
#pragma unroll
      for (int c16=0;c16<8;c16++){
        int colb = c16*16 + (l>>4)*4;
        float4 e = vet[r16*8+c16];
        *(float4*)(outf + row*128 + colb) =
          (float4){e.x + 0.01f*(acc2[r16][c16][0]+bb2v[c16].x),
                   e.y + 0.01f*(acc2[r16][c16][1]+bb2v[c16].y),
                   e.z + 0.01f*(acc2[r16][c16][2]+bb2v[c16].z),
                   e.w + 0.01f*(acc2[r16][c16][3]+bb2v[c16].w)};
      }
    }
    if (nx < NPAIR){                           // prefetch next eatt (used next epilogue)
#pragma unroll
      for (int r16=0;r16<2;r16++)
#pragma unroll
        for (int c16=0;c16<8;c16++){
          size_t row = (size_t)nx*256 + tsel*128 + wloc*32 + r16*16 + lr;
          vet[r16*8+c16] = *(const float4*)(eatt + row*128 + c16*16 + (l>>4)*4);
        }
    }
    __syncthreads();
    pr = nx;
  }
}

// ---------------- per-node gather aggregation (4 groups x float4 feats) ----------------
template<int INV, int EUPD, int ACCUM>
__global__ __launch_bounds__(128) void agg_kernel(
    const float* __restrict__ ea, float* ea_out,
    const uint16_t* __restrict__ x1, const uint16_t* __restrict__ z,
    const uint16_t* __restrict__ h3, const uint16_t* __restrict__ h4,
    const int* __restrict__ eids, const int* __restrict__ ptr,
    const int* __restrict__ other, uint16_t* stats)
{
  __shared__ int se[128];
  __shared__ int so[128];
  __shared__ float red[4][4][128];
  const int i = blockIdx.x, t = threadIdx.x;
  const int g = t >> 5, q = t & 31;
  const int f0 = q*4;
  float4 zi = unpk4(*(const uint2*)(z + (size_t)i*128 + f0));
  float4 h3i = {0,0,0,0}, h4i = {0,0,0,0};
  if (EUPD){
    h3i = unpk4(*(const uint2*)(h3 + (size_t)i*128 + f0));
    h4i = unpk4(*(const uint2*)(h4 + (size_t)i*128 + f0));
  }
  const int beg = ptr[i], end = ptr[i+1];
  float4 s={0,0,0,0}, s2={0,0,0,0};
  float4 mx={-3.4e38f,-3.4e38f,-3.4e38f,-3.4e38f}, mn={3.4e38f,3.4e38f,3.4e38f,3.4e38f};
  for (int jb = beg; jb < end; jb += 128){
    int cn = min(128, end - jb);
    if (t < cn){ int e = eids[jb+t]; se[t] = e; so[t] = other[e]; }
    __syncthreads();
#pragma unroll 2
    for (int jj = g; jj < cn; jj += 4){
      int e = se[jj], o = so[jj];
      float4 xo = unpk4(*(const uint2*)(x1 + (size_t)o*128 + f0));
      float4 ev = *(const float4*)(ea + (size_t)e*128 + f0);
      float4 m = (float4){zi.x*xo.x*ev.x, zi.y*xo.y*ev.y, zi.z*xo.z*ev.z, zi.w*xo.w*ev.w};
      if (INV){ if (q >= 16){ m.x=-m.x; m.y=-m.y; m.z=-m.z; m.w=-m.w; } }
      s.x+=m.x; s.y+=m.y; s.z+=m.z; s.w+=m.w;
      s2.x+=m.x*m.x; s2.y+=m.y*m.y; s2.z+=m.z*m.z; s2.w+=m.w*m.w;
      mx.x=fmaxf(mx.x,m.x); mx.y=fmaxf(mx.y,m.y); mx.z=fmaxf(mx.z,m.z); mx.w=fmaxf(mx.w,m.w);
      mn.x=fminf(mn.x,m.x); mn.y=fminf(mn.y,m.y); mn.z=fminf(mn.z,m.z); mn.w=fminf(mn.w,m.w);
      if (EUPD){
        float4 h3o = unpk4(*(const uint2*)(h3 + (size_t)o*128 + f0));
        float4 h4o = unpk4(*(const uint2*)(h4 + (size_t)o*128 + f0));
        *(float4*)(ea_out + (size_t)e*128 + f0) =
          (float4){ev.x*(1.f + h3o.x*h4i.x + h3i.x*h4o.x),
                   ev.y*(1.f + h3o.y*h4i.y + h3i.y*h4o.y),
                   ev.z*(1.f + h3o.z*h4i.z + h3i.z*h4o.z),
                   ev.w*(1.f + h3o.w*h4i.w + h3i.w*h4o.w)};
      }
    }
    __syncthreads();
  }
  *(float4*)(&red[g][0][f0]) = s;
  *(float4*)(&red[g][1][f0]) = s2;
  *(float4*)(&red[g][2][f0]) = mx;
  *(float4*)(&red[g][3][f0]) = mn;
  __syncthreads();
  // thread t = feature f
  float fs = red[0][0][t]+red[1][0][t]+red[2][0][t]+red[3][0][t];
  float fq = red[0][1][t]+red[1][1][t]+red[2][1][t]+red[3][1][t];
  float fmx = fmaxf(fmaxf(red[0][2][t],red[1][2][t]), fmaxf(red[2][2][t],red[3][2][t]));
  float fmn = fminf(fminf(red[0][3][t],red[1][3][t]), fminf(red[2][3][t],red[3][3][t]));
  int cnt = end - beg;
  float dn = cnt > 0 ? 1.f/(float)cnt : 1.f;
  float mean = fs*dn, m2 = fq*dn;
  float sd = sqrtf(fmaxf(m2 - mean*mean, 0.f) + 1e-5f);
  if (cnt == 0){ fmx = 0.f; fmn = 0.f; }
  size_t o0 = (size_t)i*512 + t;
  if (ACCUM){
    stats[o0    ] = f2b(b2f(stats[o0    ]) + mean);
    stats[o0+128] = f2b(b2f(stats[o0+128]) + sd);
    stats[o0+256] = f2b(b2f(stats[o0+256]) + fmx);
    stats[o0+384] = f2b(b2f(stats[o0+384]) + fmn);
  } else {
    stats[o0]=f2b(mean); stats[o0+128]=f2b(sd); stats[o0+256]=f2b(fmx); stats[o0+384]=f2b(fmn);
  }
}

// ---------------- CSR build ----------------
__global__ void count_deg(const int* __restrict__ ei, int* cnt_src, int* cnt_dst){
  int e = blockIdx.x*256 + threadIdx.x;
  if (e < EE){
    atomicAdd(&cnt_src[ei[e]], 1);
    atomicAdd(&cnt_dst[ei[EE+e]], 1);
  }
}

// single-pass scan for n = NN (C = 20 elems/thread, compile-time)
__global__ __launch_bounds__(1024) void scan20k(const int* __restrict__ cnt, int* ptr){
  __shared__ int buf[1024];
  constexpr int C = 20;
  int t = threadIdx.x;
  int base = t*C;
  int loc[C];
  int sum = 0;
#pragma unroll
  for (int j=0;j<C;j++){
    int idx = base+j;
    int v = (idx < NN) ? cnt[idx] : 0;
    loc[j] = sum; sum += v;
  }
  buf[t] = sum;
  __syncthreads();
  for (int sft=1; sft<1024; sft<<=1){
    int add = (t>=sft) ? buf[t-sft] : 0;
    __syncthreads();
    buf[t] += add;
    __syncthreads();
  }
  int excl = buf[t] - sum;
#pragma unroll
  for (int j=0;j<C;j++){
    int idx = base+j;
    if (idx < NN) ptr[idx] = excl + loc[j];
  }
  if (t == 1023) ptr[NN] = buf[1023];
}

__global__ void init_cursor(const int* p1, int* c1, const int* p2, int* c2, int n){
  int i = blockIdx.x*256 + threadIdx.x;
  if (i < n){ c1[i] = p1[i]; c2[i] = p2[i]; }
}

__global__ void scatter_edges(const int* __restrict__ ei, int* cur_src, int* cur_dst,
                              int* eid_src, int* eid_dst){
  int e = blockIdx.x*256 + threadIdx.x;
  if (e < EE){
    int s = ei[e], d = ei[EE+e];
    eid_src[atomicAdd(&cur_src[s],1)] = e;
    eid_dst[atomicAdd(&cur_dst[d],1)] = e;
  }
}

// ------- weight transpose+cast: W[m][k][c] (f32) -> Wt[m][c][k] (bf16) -------
__global__ void transpose_w(const float* __restrict__ W, uint16_t* __restrict__ Wt,
                            int K, int total){
  int idx = blockIdx.x*256 + threadIdx.x;
  if (idx < total){
    int per = K*128;
    int m = idx / per, r = idx - m*per;
    int k = r >> 7, c = r & 127;
    Wt[(size_t)m*per + (size_t)c*K + k] = f2b(W[idx]);
  }
}

extern "C" void kernel_launch(void* const* d_in, const int* in_sizes, int n_in,
                              void* d_out, int out_size, void* d_ws, size_t ws_size,
                              hipStream_t stream)
{
  const float* x    = (const float*)d_in[0];
  const float* eatt = (const float*)d_in[1];
  const float* Wn   = (const float*)d_in[2];
  const float* bn   = (const float*)d_in[3];
  const float* We   = (const float*)d_in[4];
  const float* be   = (const float*)d_in[5];
  const float* W1   = (const float*)d_in[6];
  const float* b1   = (const float*)d_in[7];
  const float* W2   = (const float*)d_in[8];
  const float* b2   = (const float*)d_in[9];
  const float* W3   = (const float*)d_in[10];
  const float* b3   = (const float*)d_in[11];
  const float* W4   = (const float*)d_in[12];
  const float* b4   = (const float*)d_in[13];
  const float* Wd   = (const float*)d_in[14];
  const float* bd   = (const float*)d_in[15];
  const float* Wnd1 = (const float*)d_in[16];
  const float* bnd1 = (const float*)d_in[17];
  const float* Wnd2 = (const float*)d_in[18];
  const float* bnd2 = (const float*)d_in[19];
  const float* Wed1 = (const float*)d_in[20];
  const float* bed1 = (const float*)d_in[21];
  const float* Wed2 = (const float*)d_in[22];
  const float* bed2 = (const float*)d_in[23];
  const int* ei     = (const int*)d_in[24];

  float* out_node = (float*)d_out;
  float* out_edge = out_node + (size_t)NN*128;
  float* ea = out_edge;   // ea (f32) lives in out_edge region; fully rewritten each call

  char* p = (char*)d_ws;
  auto alloc = [&](size_t bytes)->char*{
    char* r = p; p += (bytes + 255) & ~(size_t)255; return r; };

  float*    hidden = (float*)   alloc((size_t)NN*128*4);
  uint16_t* x1b    = (uint16_t*)alloc((size_t)NN*128*2);
  uint16_t* zb     = (uint16_t*)alloc((size_t)NN*128*2);
  uint16_t* h3b    = (uint16_t*)alloc((size_t)NN*128*2);
  uint16_t* h4b    = (uint16_t*)alloc((size_t)NN*128*2);
  uint16_t* stats  = (uint16_t*)alloc((size_t)NN*512*2);
  int* cnt_src = (int*)alloc((size_t)NN*4);
  int* cnt_dst = (int*)alloc((size_t)NN*4);
  int* ptr_src = (int*)alloc((size_t)(NN+1)*4);
  int* ptr_dst = (int*)alloc((size_t)(NN+1)*4);
  int* cur_src = (int*)alloc((size_t)NN*4);
  int* cur_dst = (int*)alloc((size_t)NN*4);
  int* eid_src = (int*)alloc((size_t)EE*4);
  int* eid_dst = (int*)alloc((size_t)EE*4);
  uint16_t* WT = (uint16_t*)alloc((size_t)491520*2);

  uint16_t* wnT   = WT;
  uint16_t* weT   = WT + 16384;
  uint16_t* w1T   = WT + 32768;
  uint16_t* w2T   = WT + 81920;
  uint16_t* w3T   = WT + 131072;
  uint16_t* w4T   = WT + 180224;
  uint16_t* wdT   = WT + 229376;
  uint16_t* wnd1T = WT + 425984;
  uint16_t* wnd2T = WT + 442368;
  uint16_t* wed1T = WT + 458752;
  uint16_t* wed2T = WT + 475136;

  // per-layer contiguous 4-projection weight block [w1|w2|w3|w4] per layer
  uint16_t* wp4 = (uint16_t*)alloc((size_t)3*4*16384*2);

  // ---- CSR build ----
  hipMemsetAsync(cnt_src, 0, (size_t)NN*4, stream);
  hipMemsetAsync(cnt_dst, 0, (size_t)NN*4, stream);
  count_deg<<<(EE+255)/256, 256, 0, stream>>>(ei, cnt_src, cnt_dst);
  scan20k<<<1, 1024, 0, stream>>>(cnt_src, ptr_src);
  scan20k<<<1, 1024, 0, stream>>>(cnt_dst, ptr_dst);
  init_cursor<<<(NN+255)/256, 256, 0, stream>>>(ptr_src, cur_src, ptr_dst, cur_dst, NN);
  scatter_edges<<<(EE+255)/256, 256, 0, stream>>>(ei, cur_src, cur_dst, eid_src, eid_dst);

  // ---- transpose+cast weights ----
  transpose_w<<<64, 256, 0, stream>>>(Wn, wnT, 128, 16384);
  transpose_w<<<64, 256, 0, stream>>>(We, weT, 128, 16384);
  transpose_w<<<192, 256, 0, stream>>>(W1, w1T, 128, 49152);
  transpose_w<<<192, 256, 0, stream>>>(W2, w2T, 128, 49152);
  transpose_w<<<192, 256, 0, stream>>>(W3, w3T, 128, 49152);
  transpose_w<<<192, 256, 0, stream>>>(W4, w4T, 128, 49152);
  transpose_w<<<768, 256, 0, stream>>>(Wd, wdT, 512, 196608);
  transpose_w<<<64, 256, 0, stream>>>(Wnd1, wnd1T, 128, 16384);
  transpose_w<<<64, 256, 0, stream>>>(Wnd2, wnd2T, 128, 16384);
  transpose_w<<<64, 256, 0, stream>>>(Wed1, wed1T, 128, 16384);
  transpose_w<<<64, 256, 0, stream>>>(Wed2, wed2T, 128, 16384);
  // pack per-layer [w1|w2|w3|w4]
  for (int lyr = 0; lyr < 3; ++lyr){
    hipMemcpyAsync(wp4 + (size_t)lyr*65536 +     0, w1T + lyr*16384, 32768, hipMemcpyDeviceToDevice, stream);
    hipMemcpyAsync(wp4 + (size_t)lyr*65536 + 16384, w2T + lyr*16384, 32768, hipMemcpyDeviceToDevice, stream);
    hipMemcpyAsync(wp4 + (size_t)lyr*65536 + 32768, w3T + lyr*16384, 32768, hipMemcpyDeviceToDevice, stream);
    hipMemcpyAsync(wp4 + (size_t)lyr*65536 + 49152, w4T + lyr*16384, 32768, hipMemcpyDeviceToDevice, stream);
  }

  const int gN = (NN+127)/128;

  // ---- encoders ----
  gemm_node<1,0,1,0><<<gN, 256, 0, stream>>>(x, wnT, bn, 1.f, NN, 128, nullptr, hidden, nullptr, 0.f);
  enc_edge<<<512, 256, 0, stream>>>(eatt, weT, be, ea);

  // ---- layers ----
  for (int lyr = 0; lyr < 3; ++lyr){
    const uint16_t* wdl = wdT + lyr*65536;
    proj4<<<gN, 256, 0, stream>>>(hidden, wp4 + (size_t)lyr*65536,
                                  b1 + lyr*128, b2 + lyr*128, b3 + lyr*128, b4 + lyr*128,
                                  x1b, zb, h3b, h4b, NN);
    agg_kernel<1,0,0><<<NN, 128, 0, stream>>>(ea, nullptr, x1b, zb, nullptr, nullptr,
                                              eid_src, ptr_src, ei + EE, stats);
    agg_kernel<0,1,1><<<NN, 128, 0, stream>>>(ea, ea, x1b, zb, h3b, h4b,
                                              eid_dst, ptr_dst, ei, stats);
    gemm_node<0,0,2,0><<<gN, 256, 0, stream>>>(stats, wdl, bd + lyr*128, 2.f, NN, 512, nullptr, hidden, nullptr, 0.f);
  }

  // ---- node decoder ----
  gemm_node<1,1,0,1><<<gN, 256, 0, stream>>>(hidden, wnd1T, bnd1, 1.f, NN, 128, x1b, nullptr, nullptr, 0.f);
  gemm_node<0,0,3,0><<<gN, 256, 0, stream>>>(x1b, wnd2T, bnd2, 1.f, NN, 128, nullptr, out_node, x, 0.01f);

  // ---- edge decoder: fused LN + GEMM1(silu) + GEMM2 + residual, in place ----
  dec_edge<<<256, 512, 0, stream>>>(ea, eatt, wed1T, wed2T, bed1, bed2, out_edge);
}

// Round 6
// 1401.304 us; speedup vs baseline: 1.6010x; 1.2166x over previous
//
#include <hip/hip_runtime.h>
#include <cstdint>
#include <cstddef>

typedef __attribute__((ext_vector_type(8))) short short8x;
typedef __attribute__((ext_vector_type(4))) float f32x4;

static constexpr int NN = 20000;
static constexpr int EE = 640000;
static constexpr int NT_E = EE / 128;    // 5000 edge row-tiles

#define DEVI __device__ __forceinline__

DEVI float b2f(uint16_t u){ union{uint32_t i; float f;} x; x.i = (uint32_t)u<<16; return x.f; }
DEVI uint16_t f2b(float f){ union{float f; uint32_t i;} x; x.f=f; uint32_t i=x.i;
  return (uint16_t)((i + 0x7FFFu + ((i>>16)&1u))>>16); }
DEVI float silu_f(float v){ return v / (1.f + __expf(-v)); }

DEVI uint4 pack8(float4 a, float4 b){
  union{uint16_t u[8]; uint4 q;} pk;
  pk.u[0]=f2b(a.x); pk.u[1]=f2b(a.y); pk.u[2]=f2b(a.z); pk.u[3]=f2b(a.w);
  pk.u[4]=f2b(b.x); pk.u[5]=f2b(b.y); pk.u[6]=f2b(b.z); pk.u[7]=f2b(b.w);
  return pk.q;
}
DEVI uint2 pack4(float4 a){
  union{uint16_t u[4]; uint2 q;} pk;
  pk.u[0]=f2b(a.x); pk.u[1]=f2b(a.y); pk.u[2]=f2b(a.z); pk.u[3]=f2b(a.w);
  return pk.q;
}
DEVI float4 unpk4(uint2 v){
  return (float4){ b2f((uint16_t)(v.x & 0xFFFFu)), b2f((uint16_t)(v.x >> 16)),
                   b2f((uint16_t)(v.y & 0xFFFFu)), b2f((uint16_t)(v.y >> 16)) };
}
DEVI short8x pk_frag(float4 a, float4 b){
  union{uint16_t u[8]; short8x s;} pk;
  pk.u[0]=f2b(a.x); pk.u[1]=f2b(a.y); pk.u[2]=f2b(a.z); pk.u[3]=f2b(a.w);
  pk.u[4]=f2b(b.x); pk.u[5]=f2b(b.y); pk.u[6]=f2b(b.z); pk.u[7]=f2b(b.w);
  return pk.s;
}

// typed helpers for ea (bf16 or f32)
template<typename EAT>
DEVI void load8e(const EAT* base, size_t row, int col8, float4& a, float4& b){
  if constexpr (sizeof(EAT)==2){
    uint4 v = *(const uint4*)((const uint16_t*)base + row*128 + col8);
    a = (float4){b2f((uint16_t)(v.x&0xFFFFu)), b2f((uint16_t)(v.x>>16)),
                 b2f((uint16_t)(v.y&0xFFFFu)), b2f((uint16_t)(v.y>>16))};
    b = (float4){b2f((uint16_t)(v.z&0xFFFFu)), b2f((uint16_t)(v.z>>16)),
                 b2f((uint16_t)(v.w&0xFFFFu)), b2f((uint16_t)(v.w>>16))};
  } else {
    const float* f = (const float*)base + row*128 + col8;
    a = *(const float4*)f; b = *(const float4*)(f+4);
  }
}
template<typename EAT>
DEVI void store4e(EAT* base, size_t idx, float4 v){
  if constexpr (sizeof(EAT)==2) *(uint2*)((uint16_t*)base + idx) = pack4(v);
  else *(float4*)((float*)base + idx) = v;
}
template<typename EAT>
DEVI float4 ld4e(const EAT* base, size_t idx){
  if constexpr (sizeof(EAT)==2) return unpk4(*(const uint2*)((const uint16_t*)base + idx));
  else return *(const float4*)((const float*)base + idx);
}

// LN a row of 128 spread over 16-lane groups holding 8 consecutive elems each
DEVI void ln8(float4& a, float4& b){
  float s = a.x+a.y+a.z+a.w + b.x+b.y+b.z+b.w;
  float q = a.x*a.x+a.y*a.y+a.z*a.z+a.w*a.w + b.x*b.x+b.y*b.y+b.z*b.z+b.w*b.w;
#pragma unroll
  for (int d=1; d<16; d<<=1){ s += __shfl_xor(s,d); q += __shfl_xor(q,d); }
  float m = s * 0.0078125f;
  float rstd = rsqrtf(fmaxf(q*0.0078125f - m*m, 0.f) + 1e-5f);
  a.x=(a.x-m)*rstd; a.y=(a.y-m)*rstd; a.z=(a.z-m)*rstd; a.w=(a.w-m)*rstd;
  b.x=(b.x-m)*rstd; b.y=(b.y-m)*rstd; b.z=(b.z-m)*rstd; b.w=(b.w-m)*rstd;
}

// =============== node-size MFMA GEMM (swapped-C epilogue) ===============
template<int AF32, int LNA, int EPI, int SILU>
__global__ __launch_bounds__(256) void gemm_node(
    const void* Ap, const uint16_t* __restrict__ Wt,
    const float* __restrict__ bias, float bias_scale,
    int M, int K,
    uint16_t* outb, float* outf,
    const float* __restrict__ resid, float resid_scale)
{
  __shared__ uint16_t Als[128*136];
  __shared__ uint16_t Wls[128*136];
  const int t = threadIdx.x;
  const int row0 = blockIdx.x * 128;
  const int w = t >> 6, l = t & 63;
  const int lr = l & 15, lk = (l>>4)*8;

  f32x4 acc[2][8];
#pragma unroll
  for (int a=0;a<2;a++)
#pragma unroll
    for(int b=0;b<8;b++) acc[a][b] = (f32x4){0.f,0.f,0.f,0.f};

  for (int kc = 0; kc < K; kc += 128){
#pragma unroll
    for (int i=0;i<8;i++){
      int c = t + i*256;
      int r = c >> 4, k8 = (c & 15)*8;
      int gr = row0 + r;
      if (AF32){
        float4 a = {0.f,0.f,0.f,0.f}, b = {0.f,0.f,0.f,0.f};
        if (gr < M){
          const float* Af = (const float*)Ap + (size_t)gr*K + kc + k8;
          a = *(const float4*)Af; b = *(const float4*)(Af + 4);
        }
        if (LNA) ln8(a, b);
        *(uint4*)(&Als[r*136 + k8]) = pack8(a, b);
      } else {
        uint4 v = {0u,0u,0u,0u};
        if (gr < M) v = *(const uint4*)((const uint16_t*)Ap + (size_t)gr*K + kc + k8);
        *(uint4*)(&Als[r*136 + k8]) = v;
      }
    }
#pragma unroll
    for (int i=0;i<8;i++){
      int c = t + i*256;
      int r = c >> 4, k8 = (c & 15)*8;
      *(uint4*)(&Wls[r*136 + k8]) = *(const uint4*)(Wt + (size_t)r*K + kc + k8);
    }
    __syncthreads();
#pragma unroll
    for (int kt=0; kt<4; ++kt){
      int kb = kt*32 + lk;
      short8x bfr[8];
#pragma unroll
      for (int c16=0;c16<8;c16++) bfr[c16] = *(const short8x*)(&Wls[(c16*16+lr)*136 + kb]);
#pragma unroll
      for (int r16=0;r16<2;r16++){
        short8x afr = *(const short8x*)(&Als[(w*32 + r16*16 + lr)*136 + kb]);
#pragma unroll
        for (int c16=0;c16<8;c16++)
          acc[r16][c16] = __builtin_amdgcn_mfma_f32_16x16x32_bf16(bfr[c16], afr, acc[r16][c16], 0,0,0);
      }
    }
    __syncthreads();
  }

  float4 bbv[8];
#pragma unroll
  for (int c16=0;c16<8;c16++){
    float4 b4 = *(const float4*)(bias + c16*16 + (l>>4)*4);
    bbv[c16] = (float4){b4.x*bias_scale, b4.y*bias_scale, b4.z*bias_scale, b4.w*bias_scale};
  }
#pragma unroll
  for (int r16=0;r16<2;r16++){
    int row = row0 + w*32 + r16*16 + lr;
    if (row >= M) continue;
#pragma unroll
    for (int c16=0;c16<8;c16++){
      int colb = c16*16 + (l>>4)*4;
      float4 v = (float4){acc[r16][c16][0]+bbv[c16].x, acc[r16][c16][1]+bbv[c16].y,
                          acc[r16][c16][2]+bbv[c16].z, acc[r16][c16][3]+bbv[c16].w};
      if (SILU){ v.x=silu_f(v.x); v.y=silu_f(v.y); v.z=silu_f(v.z); v.w=silu_f(v.w); }
      size_t o = (size_t)row*128 + colb;
      if (EPI==0)      *(uint2*)(outb + o) = pack4(v);
      else if (EPI==1) *(float4*)(outf + o) = v;
      else if (EPI==2){ float4 old = *(const float4*)(outf + o);
        *(float4*)(outf + o) = (float4){old.x+v.x, old.y+v.y, old.z+v.z, old.w+v.w}; }
      else { float4 r = *(const float4*)(resid + o);
        *(float4*)(outf + o) = (float4){r.x+resid_scale*v.x, r.y+resid_scale*v.y,
                                        r.z+resid_scale*v.z, r.w+resid_scale*v.w}; }
    }
  }
}

// ======= fused 4-projection: outp[p] = silu(LN(hidden) @ Wp + bp) =======
__global__ __launch_bounds__(256) void proj4(
    const float* __restrict__ hidden, const uint16_t* __restrict__ Wt4,
    const float* __restrict__ b0p, const float* __restrict__ b1p,
    const float* __restrict__ b2p, const float* __restrict__ b3p,
    uint16_t* o0, uint16_t* o1, uint16_t* o2, uint16_t* o3, int M)
{
  __shared__ uint16_t Als[128*136];
  __shared__ uint16_t Wls[2][128*136];
  const int t = threadIdx.x;
  const int row0 = blockIdx.x * 128;
  const int w = t >> 6, l = t & 63;
  const int lr = l & 15, lk = (l>>4)*8;

#pragma unroll
  for (int i=0;i<8;i++){
    int c = t + i*256;
    int r = c >> 4, k8 = (c & 15)*8;
    int gr = row0 + r;
    float4 a = {0.f,0.f,0.f,0.f}, b = {0.f,0.f,0.f,0.f};
    if (gr < M){
      const float* Af = hidden + (size_t)gr*128 + k8;
      a = *(const float4*)Af; b = *(const float4*)(Af + 4);
    }
    ln8(a, b);
    *(uint4*)(&Als[r*136 + k8]) = pack8(a, b);
  }
#pragma unroll
  for (int i=0;i<8;i++){
    int c = t + i*256;
    int r = c >> 4, k8 = (c & 15)*8;
    *(uint4*)(&Wls[0][r*136 + k8]) = *(const uint4*)(Wt4 + (size_t)r*128 + k8);
  }
  __syncthreads();

#pragma unroll
  for (int p=0; p<4; ++p){
    if (p < 3){
#pragma unroll
      for (int i=0;i<8;i++){
        int c = t + i*256;
        int r = c >> 4, k8 = (c & 15)*8;
        *(uint4*)(&Wls[(p+1)&1][r*136 + k8]) =
          *(const uint4*)(Wt4 + (size_t)(p+1)*16384 + (size_t)r*128 + k8);
      }
    }
    f32x4 acc[2][8];
#pragma unroll
    for (int a=0;a<2;a++)
#pragma unroll
      for(int b=0;b<8;b++) acc[a][b] = (f32x4){0.f,0.f,0.f,0.f};
#pragma unroll
    for (int kt=0; kt<4; ++kt){
      int kb = kt*32 + lk;
      short8x bfr[8];
#pragma unroll
      for (int c16=0;c16<8;c16++) bfr[c16] = *(const short8x*)(&Wls[p&1][(c16*16+lr)*136 + kb]);
#pragma unroll
      for (int r16=0;r16<2;r16++){
        short8x afr = *(const short8x*)(&Als[(w*32 + r16*16 + lr)*136 + kb]);
#pragma unroll
        for (int c16=0;c16<8;c16++)
          acc[r16][c16] = __builtin_amdgcn_mfma_f32_16x16x32_bf16(bfr[c16], afr, acc[r16][c16], 0,0,0);
      }
    }
    const float* bp = (p==0)?b0p:(p==1)?b1p:(p==2)?b2p:b3p;
    uint16_t* op = (p==0)?o0:(p==1)?o1:(p==2)?o2:o3;
#pragma unroll
    for (int r16=0;r16<2;r16++){
      int row = row0 + w*32 + r16*16 + lr;
      if (row >= M) continue;
#pragma unroll
      for (int c16=0;c16<8;c16++){
        int colb = c16*16 + (l>>4)*4;
        float4 b4 = *(const float4*)(bp + colb);
        float4 v = (float4){silu_f(acc[r16][c16][0]+b4.x), silu_f(acc[r16][c16][1]+b4.y),
                            silu_f(acc[r16][c16][2]+b4.z), silu_f(acc[r16][c16][3]+b4.w)};
        *(uint2*)(op + (size_t)row*128 + colb) = pack4(v);
      }
    }
    __syncthreads();
  }
}

// ===== edge encoder: ea = eatt @ We + be. Barrier-free, register-direct A, W from L2 =====
template<typename EAT>
__global__ __launch_bounds__(256, 2) void enc_edge(
    const float* __restrict__ A, const uint16_t* __restrict__ Wt,
    const float* __restrict__ bias, EAT* __restrict__ out)
{
  const int t = threadIdx.x, w = t >> 6, l = t & 63;
  const int lr = l & 15, g = l >> 4;
  const size_t base = (size_t)blockIdx.x*128 + w*32;

  short8x fr[2][4];
#pragma unroll
  for (int r16=0;r16<2;r16++){
#pragma unroll
    for (int kt=0;kt<4;kt++){
      const float* Af = A + (base + r16*16 + lr)*128 + kt*32 + g*8;
      float4 a = *(const float4*)Af, b = *(const float4*)(Af + 4);
      fr[r16][kt] = pk_frag(a, b);
    }
  }
  f32x4 acc[2][8];
#pragma unroll
  for (int a=0;a<2;a++)
#pragma unroll
    for (int b=0;b<8;b++) acc[a][b] = (f32x4){0.f,0.f,0.f,0.f};
#pragma unroll
  for (int kt=0;kt<4;kt++){
#pragma unroll
    for (int c16=0;c16<8;c16++){
      short8x bfr = *(const short8x*)(Wt + (size_t)(c16*16+lr)*128 + kt*32 + g*8);
      acc[0][c16] = __builtin_amdgcn_mfma_f32_16x16x32_bf16(bfr, fr[0][kt], acc[0][c16], 0,0,0);
      acc[1][c16] = __builtin_amdgcn_mfma_f32_16x16x32_bf16(bfr, fr[1][kt], acc[1][c16], 0,0,0);
    }
  }
#pragma unroll
  for (int r16=0;r16<2;r16++){
    size_t row = base + r16*16 + lr;
#pragma unroll
    for (int c16=0;c16<8;c16++){
      int colb = c16*16 + g*4;
      float4 b4 = *(const float4*)(bias + colb);
      store4e(out, row*128 + colb,
        (float4){acc[r16][c16][0]+b4.x, acc[r16][c16][1]+b4.y,
                 acc[r16][c16][2]+b4.z, acc[r16][c16][3]+b4.w});
    }
  }
}

// ===== edge decoder: out = eatt + 0.01*(silu(LN(ea)@W1+b1)@W2+b2) =====
// Barrier-free: register-direct A, W from L2, wave-private LDS stripe for P.
template<typename EAT>
__global__ __launch_bounds__(256, 2) void dec_edge(
    const EAT* ea, const float* __restrict__ eatt,
    const uint16_t* __restrict__ W1t, const uint16_t* __restrict__ W2t,
    const float* __restrict__ b1, const float* __restrict__ b2,
    float* outf)
{
  __shared__ uint16_t Pls[4][32*136];
  const int t = threadIdx.x, w = t >> 6, l = t & 63;
  const int lr = l & 15, g = l >> 4;
  uint16_t* Ps = &Pls[w][0];
  const size_t base = (size_t)blockIdx.x*128 + w*32;

  // load + LN + pack A fragments (no LDS)
  short8x fr[2][4];
#pragma unroll
  for (int r16=0;r16<2;r16++){
    float4 va[4][2];
    float s=0.f, q=0.f;
#pragma unroll
    for (int kt=0;kt<4;kt++){
      load8e(ea, base + r16*16 + lr, kt*32 + g*8, va[kt][0], va[kt][1]);
      float4 a = va[kt][0], b = va[kt][1];
      s += a.x+a.y+a.z+a.w + b.x+b.y+b.z+b.w;
      q += a.x*a.x+a.y*a.y+a.z*a.z+a.w*a.w + b.x*b.x+b.y*b.y+b.z*b.z+b.w*b.w;
    }
    s += __shfl_xor(s,16); q += __shfl_xor(q,16);
    s += __shfl_xor(s,32); q += __shfl_xor(q,32);
    float m = s*0.0078125f;
    float rstd = rsqrtf(fmaxf(q*0.0078125f - m*m, 0.f) + 1e-5f);
#pragma unroll
    for (int kt=0;kt<4;kt++){
      float4 a = va[kt][0], b = va[kt][1];
      a.x=(a.x-m)*rstd; a.y=(a.y-m)*rstd; a.z=(a.z-m)*rstd; a.w=(a.w-m)*rstd;
      b.x=(b.x-m)*rstd; b.y=(b.y-m)*rstd; b.z=(b.z-m)*rstd; b.w=(b.w-m)*rstd;
      fr[r16][kt] = pk_frag(a, b);
    }
  }
  // GEMM1 (unswapped): P[r][c], W1 frags from L2
  f32x4 acc[2][8];
#pragma unroll
  for (int a=0;a<2;a++)
#pragma unroll
    for (int b=0;b<8;b++) acc[a][b] = (f32x4){0.f,0.f,0.f,0.f};
#pragma unroll
  for (int kt=0;kt<4;kt++){
#pragma unroll
    for (int c16=0;c16<8;c16++){
      short8x bfr = *(const short8x*)(W1t + (size_t)(c16*16+lr)*128 + kt*32 + g*8);
      acc[0][c16] = __builtin_amdgcn_mfma_f32_16x16x32_bf16(fr[0][kt], bfr, acc[0][c16], 0,0,0);
      acc[1][c16] = __builtin_amdgcn_mfma_f32_16x16x32_bf16(fr[1][kt], bfr, acc[1][c16], 0,0,0);
    }
  }
  // silu+b1 -> wave-private P stripe (no barrier needed)
#pragma unroll
  for (int c16=0;c16<8;c16++){
    float bb = b1[c16*16+lr];
#pragma unroll
    for (int r16=0;r16<2;r16++)
#pragma unroll
      for (int j=0;j<4;j++)
        Ps[(r16*16 + g*4 + j)*136 + c16*16 + lr] = f2b(silu_f(acc[r16][c16][j] + bb));
  }
  // GEMM2 (swapped -> row-contig out): A = P stripe, W2 frags from L2
  f32x4 acc2[2][8];
#pragma unroll
  for (int a=0;a<2;a++)
#pragma unroll
    for (int b=0;b<8;b++) acc2[a][b] = (f32x4){0.f,0.f,0.f,0.f};
#pragma unroll
  for (int kt=0;kt<4;kt++){
    short8x a0 = *(const short8x*)(Ps + (0*16 + lr)*136 + kt*32 + g*8);
    short8x a1 = *(const short8x*)(Ps + (1*16 + lr)*136 + kt*32 + g*8);
#pragma unroll
    for (int c16=0;c16<8;c16++){
      short8x bfr = *(const short8x*)(W2t + (size_t)(c16*16+lr)*128 + kt*32 + g*8);
      acc2[0][c16] = __builtin_amdgcn_mfma_f32_16x16x32_bf16(bfr, a0, acc2[0][c16], 0,0,0);
      acc2[1][c16] = __builtin_amdgcn_mfma_f32_16x16x32_bf16(bfr, a1, acc2[1][c16], 0,0,0);
    }
  }
  // epilogue
#pragma unroll
  for (int r16=0;r16<2;r16++){
    size_t row = base + r16*16 + lr;
    float4 et[8];
#pragma unroll
    for (int c16=0;c16<8;c16++) et[c16] = *(const float4*)(eatt + row*128 + c16*16 + g*4);
#pragma unroll
    for (int c16=0;c16<8;c16++){
      int colb = c16*16 + g*4;
      float4 bb = *(const float4*)(b2 + colb);
      *(float4*)(outf + row*128 + colb) =
        (float4){et[c16].x + 0.01f*(acc2[r16][c16][0]+bb.x),
                 et[c16].y + 0.01f*(acc2[r16][c16][1]+bb.y),
                 et[c16].z + 0.01f*(acc2[r16][c16][2]+bb.z),
                 et[c16].w + 0.01f*(acc2[r16][c16][3]+bb.w)};
    }
  }
}

// ---------------- per-node gather aggregation (4 groups x float4 feats) ----------------
template<typename EAT, int INV, int EUPD, int ACCUM>
__global__ __launch_bounds__(128) void agg_kernel(
    const EAT* ea, EAT* ea_out,
    const uint16_t* __restrict__ x1, const uint16_t* __restrict__ z,
    const uint16_t* __restrict__ h3, const uint16_t* __restrict__ h4,
    const int* __restrict__ eids, const int* __restrict__ ptr,
    const int* __restrict__ other, uint16_t* stats)
{
  __shared__ int se[128];
  __shared__ int so[128];
  __shared__ float red[4][4][128];
  const int i = blockIdx.x, t = threadIdx.x;
  const int g = t >> 5, q = t & 31;
  const int f0 = q*4;
  float4 zi = unpk4(*(const uint2*)(z + (size_t)i*128 + f0));
  float4 h3i = {0,0,0,0}, h4i = {0,0,0,0};
  if (EUPD){
    h3i = unpk4(*(const uint2*)(h3 + (size_t)i*128 + f0));
    h4i = unpk4(*(const uint2*)(h4 + (size_t)i*128 + f0));
  }
  const int beg = ptr[i], end = ptr[i+1];
  float4 s={0,0,0,0}, s2={0,0,0,0};
  float4 mx={-3.4e38f,-3.4e38f,-3.4e38f,-3.4e38f}, mn={3.4e38f,3.4e38f,3.4e38f,3.4e38f};
  for (int jb = beg; jb < end; jb += 128){
    int cn = min(128, end - jb);
    if (t < cn){ int e = eids[jb+t]; se[t] = e; so[t] = other[e]; }
    __syncthreads();
#pragma unroll 2
    for (int jj = g; jj < cn; jj += 4){
      int e = se[jj], o = so[jj];
      float4 xo = unpk4(*(const uint2*)(x1 + (size_t)o*128 + f0));
      float4 ev = ld4e(ea, (size_t)e*128 + f0);
      float4 m = (float4){zi.x*xo.x*ev.x, zi.y*xo.y*ev.y, zi.z*xo.z*ev.z, zi.w*xo.w*ev.w};
      if (INV){ if (q >= 16){ m.x=-m.x; m.y=-m.y; m.z=-m.z; m.w=-m.w; } }
      s.x+=m.x; s.y+=m.y; s.z+=m.z; s.w+=m.w;
      s2.x+=m.x*m.x; s2.y+=m.y*m.y; s2.z+=m.z*m.z; s2.w+=m.w*m.w;
      mx.x=fmaxf(mx.x,m.x); mx.y=fmaxf(mx.y,m.y); mx.z=fmaxf(mx.z,m.z); mx.w=fmaxf(mx.w,m.w);
      mn.x=fminf(mn.x,m.x); mn.y=fminf(mn.y,m.y); mn.z=fminf(mn.z,m.z); mn.w=fminf(mn.w,m.w);
      if (EUPD){
        float4 h3o = unpk4(*(const uint2*)(h3 + (size_t)o*128 + f0));
        float4 h4o = unpk4(*(const uint2*)(h4 + (size_t)o*128 + f0));
        store4e(ea_out, (size_t)e*128 + f0,
          (float4){ev.x*(1.f + h3o.x*h4i.x + h3i.x*h4o.x),
                   ev.y*(1.f + h3o.y*h4i.y + h3i.y*h4o.y),
                   ev.z*(1.f + h3o.z*h4i.z + h3i.z*h4o.z),
                   ev.w*(1.f + h3o.w*h4i.w + h3i.w*h4o.w)});
      }
    }
    __syncthreads();
  }
  *(float4*)(&red[g][0][f0]) = s;
  *(float4*)(&red[g][1][f0]) = s2;
  *(float4*)(&red[g][2][f0]) = mx;
  *(float4*)(&red[g][3][f0]) = mn;
  __syncthreads();
  float fs = red[0][0][t]+red[1][0][t]+red[2][0][t]+red[3][0][t];
  float fq = red[0][1][t]+red[1][1][t]+red[2][1][t]+red[3][1][t];
  float fmx = fmaxf(fmaxf(red[0][2][t],red[1][2][t]), fmaxf(red[2][2][t],red[3][2][t]));
  float fmn = fminf(fminf(red[0][3][t],red[1][3][t]), fminf(red[2][3][t],red[3][3][t]));
  int cnt = end - beg;
  float dn = cnt > 0 ? 1.f/(float)cnt : 1.f;
  float mean = fs*dn, m2 = fq*dn;
  float sd = sqrtf(fmaxf(m2 - mean*mean, 0.f) + 1e-5f);
  if (cnt == 0){ fmx = 0.f; fmn = 0.f; }
  size_t o0 = (size_t)i*512 + t;
  if (ACCUM){
    stats[o0    ] = f2b(b2f(stats[o0    ]) + mean);
    stats[o0+128] = f2b(b2f(stats[o0+128]) + sd);
    stats[o0+256] = f2b(b2f(stats[o0+256]) + fmx);
    stats[o0+384] = f2b(b2f(stats[o0+384]) + fmn);
  } else {
    stats[o0]=f2b(mean); stats[o0+128]=f2b(sd); stats[o0+256]=f2b(fmx); stats[o0+384]=f2b(fmn);
  }
}

// ---------------- CSR build ----------------
__global__ void count_deg(const int* __restrict__ ei, int* cnt_src, int* cnt_dst){
  int e = blockIdx.x*256 + threadIdx.x;
  if (e < EE){
    atomicAdd(&cnt_src[ei[e]], 1);
    atomicAdd(&cnt_dst[ei[EE+e]], 1);
  }
}

__global__ __launch_bounds__(1024) void scan20k(const int* __restrict__ cnt, int* ptr){
  __shared__ int buf[1024];
  constexpr int C = 20;
  int t = threadIdx.x;
  int base = t*C;
  int loc[C];
  int sum = 0;
#pragma unroll
  for (int j=0;j<C;j++){
    int idx = base+j;
    int v = (idx < NN) ? cnt[idx] : 0;
    loc[j] = sum; sum += v;
  }
  buf[t] = sum;
  __syncthreads();
  for (int sft=1; sft<1024; sft<<=1){
    int add = (t>=sft) ? buf[t-sft] : 0;
    __syncthreads();
    buf[t] += add;
    __syncthreads();
  }
  int excl = buf[t] - sum;
#pragma unroll
  for (int j=0;j<C;j++){
    int idx = base+j;
    if (idx < NN) ptr[idx] = excl + loc[j];
  }
  if (t == 1023) ptr[NN] = buf[1023];
}

__global__ void init_cursor(const int* p1, int* c1, const int* p2, int* c2, int n){
  int i = blockIdx.x*256 + threadIdx.x;
  if (i < n){ c1[i] = p1[i]; c2[i] = p2[i]; }
}

__global__ void scatter_edges(const int* __restrict__ ei, int* cur_src, int* cur_dst,
                              int* eid_src, int* eid_dst){
  int e = blockIdx.x*256 + threadIdx.x;
  if (e < EE){
    int s = ei[e], d = ei[EE+e];
    eid_src[atomicAdd(&cur_src[s],1)] = e;
    eid_dst[atomicAdd(&cur_dst[d],1)] = e;
  }
}

// ------- weight transpose+cast with slotted output -------
__global__ void transpose_w(const float* __restrict__ W, uint16_t* __restrict__ Wt,
                            int K, int total, int ostride, int ooff){
  int idx = blockIdx.x*256 + threadIdx.x;
  if (idx < total){
    int per = K*128;
    int m = idx / per, r = idx - m*per;
    int k = r >> 7, c = r & 127;
    Wt[(size_t)m*ostride + ooff + (size_t)c*K + k] = f2b(W[idx]);
  }
}

extern "C" void kernel_launch(void* const* d_in, const int* in_sizes, int n_in,
                              void* d_out, int out_size, void* d_ws, size_t ws_size,
                              hipStream_t stream)
{
  const float* x    = (const float*)d_in[0];
  const float* eatt = (const float*)d_in[1];
  const float* Wn   = (const float*)d_in[2];
  const float* bn   = (const float*)d_in[3];
  const float* We   = (const float*)d_in[4];
  const float* be   = (const float*)d_in[5];
  const float* W1   = (const float*)d_in[6];
  const float* b1   = (const float*)d_in[7];
  const float* W2   = (const float*)d_in[8];
  const float* b2   = (const float*)d_in[9];
  const float* W3   = (const float*)d_in[10];
  const float* b3   = (const float*)d_in[11];
  const float* W4   = (const float*)d_in[12];
  const float* b4   = (const float*)d_in[13];
  const float* Wd   = (const float*)d_in[14];
  const float* bd   = (const float*)d_in[15];
  const float* Wnd1 = (const float*)d_in[16];
  const float* bnd1 = (const float*)d_in[17];
  const float* Wnd2 = (const float*)d_in[18];
  const float* bnd2 = (const float*)d_in[19];
  const float* Wed1 = (const float*)d_in[20];
  const float* bed1 = (const float*)d_in[21];
  const float* Wed2 = (const float*)d_in[22];
  const float* bed2 = (const float*)d_in[23];
  const int* ei     = (const int*)d_in[24];

  float* out_node = (float*)d_out;
  float* out_edge = out_node + (size_t)NN*128;

  char* p = (char*)d_ws;
  auto alloc = [&](size_t bytes)->char*{
    char* r = p; p += (bytes + 255) & ~(size_t)255; return r; };

  float*    hidden = (float*)   alloc((size_t)NN*128*4);
  uint16_t* x1b    = (uint16_t*)alloc((size_t)NN*128*2);
  uint16_t* zb     = (uint16_t*)alloc((size_t)NN*128*2);
  uint16_t* h3b    = (uint16_t*)alloc((size_t)NN*128*2);
  uint16_t* h4b    = (uint16_t*)alloc((size_t)NN*128*2);
  uint16_t* stats  = (uint16_t*)alloc((size_t)NN*512*2);
  int* cnt_src = (int*)alloc((size_t)NN*4);
  int* cnt_dst = (int*)alloc((size_t)NN*4);
  int* ptr_src = (int*)alloc((size_t)(NN+1)*4);
  int* ptr_dst = (int*)alloc((size_t)(NN+1)*4);
  int* cur_src = (int*)alloc((size_t)NN*4);
  int* cur_dst = (int*)alloc((size_t)NN*4);
  int* eid_src = (int*)alloc((size_t)EE*4);
  int* eid_dst = (int*)alloc((size_t)EE*4);
  uint16_t* WT  = (uint16_t*)alloc((size_t)294912*2);   // wn|we|wd|wnd1|wnd2|wed1|wed2
  uint16_t* wp4 = (uint16_t*)alloc((size_t)3*65536*2);  // per-layer [w1|w2|w3|w4]

  uint16_t* wnT   = WT;
  uint16_t* weT   = WT + 16384;
  uint16_t* wdT   = WT + 32768;
  uint16_t* wnd1T = WT + 229376;
  uint16_t* wnd2T = WT + 245760;
  uint16_t* wed1T = WT + 262144;
  uint16_t* wed2T = WT + 278528;

  // ea: bf16 in ws if it fits, else f32 in the out_edge region (fallback)
  size_t used = (size_t)(p - (char*)d_ws);
  bool ea16ok = (ws_size >= used + (size_t)EE*128*2 + 512);
  uint16_t* ea16 = nullptr;
  if (ea16ok) ea16 = (uint16_t*)alloc((size_t)EE*128*2);
  float* eaf = out_edge;

  // ---- CSR build ----
  hipMemsetAsync(cnt_src, 0, (size_t)NN*4, stream);
  hipMemsetAsync(cnt_dst, 0, (size_t)NN*4, stream);
  count_deg<<<(EE+255)/256, 256, 0, stream>>>(ei, cnt_src, cnt_dst);
  scan20k<<<1, 1024, 0, stream>>>(cnt_src, ptr_src);
  scan20k<<<1, 1024, 0, stream>>>(cnt_dst, ptr_dst);
  init_cursor<<<(NN+255)/256, 256, 0, stream>>>(ptr_src, cur_src, ptr_dst, cur_dst, NN);
  scatter_edges<<<(EE+255)/256, 256, 0, stream>>>(ei, cur_src, cur_dst, eid_src, eid_dst);

  // ---- transpose+cast weights ----
  transpose_w<<<64, 256, 0, stream>>>(Wn, wnT, 128, 16384, 16384, 0);
  transpose_w<<<64, 256, 0, stream>>>(We, weT, 128, 16384, 16384, 0);
  transpose_w<<<192, 256, 0, stream>>>(W1, wp4, 128, 49152, 65536, 0);
  transpose_w<<<192, 256, 0, stream>>>(W2, wp4, 128, 49152, 65536, 16384);
  transpose_w<<<192, 256, 0, stream>>>(W3, wp4, 128, 49152, 65536, 32768);
  transpose_w<<<192, 256, 0, stream>>>(W4, wp4, 128, 49152, 65536, 49152);
  transpose_w<<<768, 256, 0, stream>>>(Wd, wdT, 512, 196608, 65536, 0);
  transpose_w<<<64, 256, 0, stream>>>(Wnd1, wnd1T, 128, 16384, 16384, 0);
  transpose_w<<<64, 256, 0, stream>>>(Wnd2, wnd2T, 128, 16384, 16384, 0);
  transpose_w<<<64, 256, 0, stream>>>(Wed1, wed1T, 128, 16384, 16384, 0);
  transpose_w<<<64, 256, 0, stream>>>(Wed2, wed2T, 128, 16384, 16384, 0);

  const int gN = (NN+127)/128;

  // ---- node encoder ----
  gemm_node<1,0,1,0><<<gN, 256, 0, stream>>>(x, wnT, bn, 1.f, NN, 128, nullptr, hidden, nullptr, 0.f);

  if (ea16ok){
    enc_edge<uint16_t><<<NT_E, 256, 0, stream>>>(eatt, weT, be, ea16);
    for (int lyr = 0; lyr < 3; ++lyr){
      proj4<<<gN, 256, 0, stream>>>(hidden, wp4 + (size_t)lyr*65536,
                                    b1 + lyr*128, b2 + lyr*128, b3 + lyr*128, b4 + lyr*128,
                                    x1b, zb, h3b, h4b, NN);
      agg_kernel<uint16_t,1,0,0><<<NN, 128, 0, stream>>>(ea16, nullptr, x1b, zb, nullptr, nullptr,
                                                         eid_src, ptr_src, ei + EE, stats);
      agg_kernel<uint16_t,0,1,1><<<NN, 128, 0, stream>>>(ea16, ea16, x1b, zb, h3b, h4b,
                                                         eid_dst, ptr_dst, ei, stats);
      gemm_node<0,0,2,0><<<gN, 256, 0, stream>>>(stats, wdT + lyr*65536, bd + lyr*128, 2.f,
                                                 NN, 512, nullptr, hidden, nullptr, 0.f);
    }
  } else {
    enc_edge<float><<<NT_E, 256, 0, stream>>>(eatt, weT, be, eaf);
    for (int lyr = 0; lyr < 3; ++lyr){
      proj4<<<gN, 256, 0, stream>>>(hidden, wp4 + (size_t)lyr*65536,
                                    b1 + lyr*128, b2 + lyr*128, b3 + lyr*128, b4 + lyr*128,
                                    x1b, zb, h3b, h4b, NN);
      agg_kernel<float,1,0,0><<<NN, 128, 0, stream>>>(eaf, nullptr, x1b, zb, nullptr, nullptr,
                                                      eid_src, ptr_src, ei + EE, stats);
      agg_kernel<float,0,1,1><<<NN, 128, 0, stream>>>(eaf, eaf, x1b, zb, h3b, h4b,
                                                      eid_dst, ptr_dst, ei, stats);
      gemm_node<0,0,2,0><<<gN, 256, 0, stream>>>(stats, wdT + lyr*65536, bd + lyr*128, 2.f,
                                                 NN, 512, nullptr, hidden, nullptr, 0.f);
    }
  }

  // ---- node decoder ----
  gemm_node<1,1,0,1><<<gN, 256, 0, stream>>>(hidden, wnd1T, bnd1, 1.f, NN, 128, x1b, nullptr, nullptr, 0.f);
  gemm_node<0,0,3,0><<<gN, 256, 0, stream>>>(x1b, wnd2T, bnd2, 1.f, NN, 128, nullptr, out_node, x, 0.01f);

  // ---- edge decoder ----
  if (ea16ok)
    dec_edge<uint16_t><<<NT_E, 256, 0, stream>>>(ea16, eatt, wed1T, wed2T, bed1, bed2, out_edge);
  else
    dec_edge<float><<<NT_E, 256, 0, stream>>>(eaf, eatt, wed1T, wed2T, bed1, bed2, out_edge);
}